// Round 5
// baseline (822.512 us; speedup 1.0000x reference)
//
#include <hip/hip_runtime.h>
#include <hip/hip_bf16.h>
#include <math.h>

// ---------------------------------------------------------------------------
// Fully fused transformer block, TRANSPOSED-GEMM formulation.
// One workgroup (512 thr = 8 waves) per 64-token window; 8192 windows.
// Round 5: register-pressure restructure to reach 3 blocks/CU WITHOUT spill.
//  Evidence: r3 (VGPR 40 + 48KB LDS) -> occ 62.8% (3 blocks, but spilled);
//  r4 (VGPR 64 arch + accs) -> occ 45.7% (2 blocks, no spill, dur flat).
//  => LDS admits 3 blocks; TOTAL regs (arch+acc, unified file) must fit the
//  6-waves/SIMD granule (~85). Changes:
//   * stage 3: tt-outer, Q/K/V MFMAs fused over one shared Bfr[4] (16 regs)
//     instead of Bfr[4][4] (64 regs). Q accs carried across the n1 barrier.
//   * stage 7: tt-outer, same trick (no 64-reg preload).
//   * stage 4: S processed per-kt (one f32x4 live, not S[4]).
//   * stage 9: wave owns (token-tile, ct-pair) -> 128 B contiguous per token
//     row per wave (write inflation 4x -> ~2x).
//   * __launch_bounds__(512, 6) now that demand is structurally ~80.
//  Numerics identical to round 4 (verified absmax 0.074).
// Layouts (guide §3, HW-verified): A[m=lane&15][k=quad*8+j],
// B[k=quad*8+j][n=lane&15], D[row=quad*4+reg][col=lane&15].
// ---------------------------------------------------------------------------

typedef __bf16 bf16;
typedef __bf16 bf16x8 __attribute__((ext_vector_type(8)));
typedef __bf16 bf16x4 __attribute__((ext_vector_type(4)));
typedef float  f32x4  __attribute__((ext_vector_type(4)));

#define MFMA16(a, b, c) __builtin_amdgcn_mfma_f32_16x16x32_bf16((a), (b), (c), 0, 0, 0)

// packed-weight element offsets inside d_ws (bf16 elements)
constexpr int OFF_PRE  = 0;       // w_pre  64x128 : KT=2, MT=8  -> 16 tiles
constexpr int OFF_QKV  = 8192;    // w_qkv 128x384 : KT=4, MT=24 -> 96 tiles
constexpr int OFF_PROJ = 57344;   // w_proj128x128 : KT=4, MT=8  -> 32 tiles
constexpr int OFF_M1   = 73728;   // w_m1  128x256 : KT=4, MT=16 -> 64 tiles
constexpr int OFF_M2   = 106496;  // w_m2  256x128 : KT=8, MT=8  -> 64 tiles
constexpr int OFF_POST = 139264;  // w_post128x64  : KT=4, MT=4  -> 16 tiles
// total 147456 bf16 = 288 KB in d_ws

// XOR-swizzled row-major layout (16B chunks XOR row) -> conflict-light
// ds_read_b128 / ds_write_b64 without padding.
template <int W>
__device__ __forceinline__ int swz(int row, int col) {
    constexpr int CH = W >> 3;
    constexpr int M  = (CH - 1) < 15 ? (CH - 1) : 15;
    const int c = (col >> 3) ^ (row & M);
    return row * W + c * 8 + (col & 7);
}

__device__ __forceinline__ bf16x8 zero8() {
    bf16x8 z;
#pragma unroll
    for (int j = 0; j < 8; ++j) z[j] = (bf16)0.0f;
    return z;
}

// store 4 fp32 as 4 consecutive bf16 (8B). col base is 4-aligned -> stays
// inside one 8-elem swizzle chunk -> single ds_write_b64.
__device__ __forceinline__ void st4(bf16* p, const f32x4 v) {
    bf16x4 o;
#pragma unroll
    for (int r = 0; r < 4; ++r) o[r] = (bf16)v[r];
    *(bf16x4*)p = o;
}

// fast gelu: x * sigmoid(2u), u = 0.79788456(x + 0.044715 x^3)
__device__ __forceinline__ float gelu_f(float x) {
    const float u = 0.79788456f * x * (1.0f + 0.044715f * x * x);
    const float e = __builtin_amdgcn_exp2f(u * 2.8853900817779268f);  // e^(2u)
    return x - x * __builtin_amdgcn_rcpf(e + 1.0f);  // robust at e->inf
}

// ---------------------------------------------------------------------------
// Weight packer: fp32 W[K][N] -> A-frag tiles of W^T (== B-frag tiles of W).
// Tile (mt,kt): lane l, frag[j] = W[kt*32 + (l>>4)*8 + j][mt*16 + (l&15)].
// All six weights in ONE kernel (288 blocks) to avoid 6 launch latencies.
// ---------------------------------------------------------------------------
__global__ void pack_all(const float* __restrict__ w_pre,
                         const float* __restrict__ w_qkv,
                         const float* __restrict__ w_proj,
                         const float* __restrict__ w_m1,
                         const float* __restrict__ w_m2,
                         const float* __restrict__ w_post,
                         bf16* __restrict__ dst) {
    const int t = blockIdx.x;
    const float* src;
    int Ncol, KT, off, t0;
    if (t < 16)       { src = w_pre;  Ncol = 128; KT = 2; off = OFF_PRE;  t0 = 0; }
    else if (t < 112) { src = w_qkv;  Ncol = 384; KT = 4; off = OFF_QKV;  t0 = 16; }
    else if (t < 144) { src = w_proj; Ncol = 128; KT = 4; off = OFF_PROJ; t0 = 112; }
    else if (t < 208) { src = w_m1;   Ncol = 256; KT = 4; off = OFF_M1;   t0 = 144; }
    else if (t < 272) { src = w_m2;   Ncol = 128; KT = 8; off = OFF_M2;   t0 = 208; }
    else              { src = w_post; Ncol = 64;  KT = 4; off = OFF_POST; t0 = 272; }
    const int tile = t - t0;
    const int lane = threadIdx.x;
    const int mt = tile / KT, kt = tile - mt * KT;
    const int n  = mt * 16 + (lane & 15);
    const int k0 = kt * 32 + (lane >> 4) * 8;
    bf16x8 v;
#pragma unroll
    for (int j = 0; j < 8; ++j) v[j] = (bf16)src[(k0 + j) * Ncol + n];
    // NOTE: destination MUST include the per-weight region offset `off`.
    *(bf16x8*)(dst + off + ((long)(tile * 64 + lane)) * 8) = v;
}

// LayerNorm over 128 channels: 8 lanes per row, shuffle-reduce, bf16 out.
__device__ __forceinline__ void ln_rows(const bf16* __restrict__ in,
                                        bf16* __restrict__ outb,
                                        const float* __restrict__ g,
                                        const float* __restrict__ b, int tid) {
    const int row = tid >> 3, sub = tid & 7;
    bf16x8 c0 = *(const bf16x8*)(in + swz<128>(row, sub * 16));
    bf16x8 c1 = *(const bf16x8*)(in + swz<128>(row, sub * 16 + 8));
    float v[16];
#pragma unroll
    for (int j = 0; j < 8; ++j) { v[j] = (float)c0[j]; v[8 + j] = (float)c1[j]; }
    float s = 0.f, ss = 0.f;
#pragma unroll
    for (int j = 0; j < 16; ++j) { s += v[j]; ss += v[j] * v[j]; }
#pragma unroll
    for (int m = 1; m <= 4; m <<= 1) {
        s += __shfl_xor(s, m);
        ss += __shfl_xor(ss, m);
    }
    const float mu   = s * (1.0f / 128.0f);
    const float rstd = __builtin_amdgcn_rsqf(ss * (1.0f / 128.0f) - mu * mu + 1e-5f);
    bf16x8 o0, o1;
#pragma unroll
    for (int j = 0; j < 8; ++j) {
        o0[j] = (bf16)((v[j] - mu) * rstd * g[sub * 16 + j] + b[sub * 16 + j]);
        o1[j] = (bf16)((v[8 + j] - mu) * rstd * g[sub * 16 + 8 + j] + b[sub * 16 + 8 + j]);
    }
    *(bf16x8*)(outb + swz<128>(row, sub * 16)) = o0;
    *(bf16x8*)(outb + swz<128>(row, sub * 16 + 8)) = o1;
}

__global__ __launch_bounds__(512, 6)
void fused_block_kernel(const float* __restrict__ feats,
                        const bf16* __restrict__ wp,
                        const float* __restrict__ b_pre,
                        const float* __restrict__ g1, const float* __restrict__ b1,
                        const float* __restrict__ b_qkv,
                        const float* __restrict__ b_proj,
                        const float* __restrict__ g2, const float* __restrict__ b2,
                        const float* __restrict__ b_m1,
                        const float* __restrict__ b_m2,
                        const float* __restrict__ b_post,
                        float* __restrict__ out) {
    // 48 KB static LDS, three 16 KB regions, time-multiplexed:
    //  RA: feats(8KB, swz<64>) -> n1 -> Q -> O -> n2 -> x2_bf16(post input)
    //  RB: x2_bf16(LN1 in) -> K -> x2_bf16(LN2 in) -> hidden[:,0:128]
    //  RC: per-wave slabs (V^T then P, 1024 elems each) -> hidden[:,128:256]
    // Lifetime rules: a region is overwritten only after (a) an all-wave
    // barrier past its last cross-wave read, or (b) it is same-wave-private.
    __shared__ __align__(16) bf16 RA[64 * 128];
    __shared__ __align__(16) bf16 RB[64 * 128];
    __shared__ __align__(16) bf16 RC[64 * 128];

    const int tid  = threadIdx.x;
    const int w    = tid >> 6;   // wave 0..7 == head / out-channel-tile owner
    const int lane = tid & 63;
    const int q    = lane >> 4;  // quad
    const int l15  = lane & 15;
    const long base = (long)blockIdx.x * 64;
    const f32x4 fzero = {0.f, 0.f, 0.f, 0.f};

    // -------- stage 0: feats (64x64 fp32) -> RA bf16, swizzled --------------
    {
        const int row = tid >> 3, ch = tid & 7;
        const float* src = feats + (base + row) * 64 + ch * 8;
        float4 a = *(const float4*)src;
        float4 b = *(const float4*)(src + 4);
        bf16x8 v;
        v[0] = (bf16)a.x; v[1] = (bf16)a.y; v[2] = (bf16)a.z; v[3] = (bf16)a.w;
        v[4] = (bf16)b.x; v[5] = (bf16)b.y; v[6] = (bf16)b.z; v[7] = (bf16)b.w;
        *(bf16x8*)(RA + swz<64>(row, ch * 8)) = v;
    }
    __syncthreads();

    // residual stream in regs: x2[tt][r] = x2[token tt*16+l15][ch w*16+q*4+r]
    f32x4 x2[4];

    // -------- stage 1: x2^T = w_pre^T . feats^T + b_pre; x2_bf16 -> RB ------
    {
        f32x4 acc[4];
#pragma unroll
        for (int tt = 0; tt < 4; ++tt) acc[tt] = fzero;
#pragma unroll
        for (int ks = 0; ks < 2; ++ks) {
            bf16x8 afr = *(const bf16x8*)(wp + OFF_PRE + ((w * 2 + ks) * 64 + lane) * 8);
#pragma unroll
            for (int tt = 0; tt < 4; ++tt) {
                bf16x8 bfr = *(const bf16x8*)(RA + swz<64>(tt * 16 + l15, ks * 32 + q * 8));
                acc[tt] = MFMA16(afr, bfr, acc[tt]);
            }
        }
        const f32x4 bias = *(const f32x4*)(b_pre + w * 16 + q * 4);
#pragma unroll
        for (int tt = 0; tt < 4; ++tt) {
#pragma unroll
            for (int r = 0; r < 4; ++r) x2[tt][r] = acc[tt][r] + bias[r];
            st4(RB + swz<128>(tt * 16 + l15, w * 16 + q * 4), x2[tt]);
        }
    }
    __syncthreads();

    // -------- stage 2: n1 = LN(x2)*g1+b1 : RB -> RA -------------------------
    ln_rows(RB, RA, g1, b1, tid);
    __syncthreads();

    // -------- stage 3: qkv^T = w_qkv^T . n1^T + b_qkv (tt-outer) ------------
    // Per token-tile: ONE shared Bfr[4] (16 regs) feeds Q,K,V MFMAs (same
    // products, same ks order as the old per-part loops -> bit-identical).
    // K -> RB (dead post-LN1), V -> RC slab (dead), Q -> regs; after the
    // n1-protection barrier Q is stored to RA.  Peak regs ~80, no 64-reg
    // Bfr[4][4] preload.
    {
        f32x4 accQ[4];
#pragma unroll
        for (int tt = 0; tt < 4; ++tt) {
            bf16x8 Bfr[4];
#pragma unroll
            for (int ks = 0; ks < 4; ++ks)
                Bfr[ks] = *(const bf16x8*)(RA + swz<128>(tt * 16 + l15, ks * 32 + q * 8));
            f32x4 aQ = fzero, aK = fzero, aV = fzero;
#pragma unroll
            for (int ks = 0; ks < 4; ++ks) {
                bf16x8 afQ = *(const bf16x8*)(wp + OFF_QKV + (((0  + w) * 4 + ks) * 64 + lane) * 8);
                aQ = MFMA16(afQ, Bfr[ks], aQ);
                bf16x8 afK = *(const bf16x8*)(wp + OFF_QKV + (((8  + w) * 4 + ks) * 64 + lane) * 8);
                aK = MFMA16(afK, Bfr[ks], aK);
                bf16x8 afV = *(const bf16x8*)(wp + OFF_QKV + (((16 + w) * 4 + ks) * 64 + lane) * 8);
                aV = MFMA16(afV, Bfr[ks], aV);
            }
            accQ[tt] = aQ;
            {
                const f32x4 bK = *(const f32x4*)(b_qkv + (8 + w) * 16 + q * 4);
                st4(RB + swz<128>(tt * 16 + l15, w * 16 + q * 4), aK + bK);
            }
            {
                const f32x4 bV = *(const f32x4*)(b_qkv + (16 + w) * 16 + q * 4);
#pragma unroll
                for (int r = 0; r < 4; ++r)
                    RC[w * 1024 + swz<64>(q * 4 + r, tt * 16 + l15)] =
                        (bf16)(aV[r] + bV[r]);
            }
        }
        __syncthreads();  // all waves done reading n1; RA writable
        const f32x4 bQ = *(const f32x4*)(b_qkv + w * 16 + q * 4);
#pragma unroll
        for (int tt = 0; tt < 4; ++tt)
            st4(RA + swz<128>(tt * 16 + l15, w * 16 + q * 4), accQ[tt] + bQ);
    }
    __syncthreads();  // conservative (stage-4 reads are same-wave; keep r2 semantics)

    // -------- stage 4: attention (wave w = head w), S^T = K.Q^T -------------
    {
        const int colA = w * 16 + (q & 1) * 8;  // HD=16: quads>=2 zero-padded
        const bool hi = (q >= 2);
        const bf16x8 z8 = zero8();
        bf16* const slab = RC + w * 1024;  // [16][64] swz<64>: V^T, then P
        bf16x8 Kf[4];
#pragma unroll
        for (int kt = 0; kt < 4; ++kt) {
            bf16x8 t = *(const bf16x8*)(RB + swz<128>(kt * 16 + l15, colA));
            Kf[kt] = hi ? z8 : t;
        }
        // V frags are qt-independent: load once, then the slab is free for P.
        bf16x8 Vf[2];
#pragma unroll
        for (int ks = 0; ks < 2; ++ks)
            Vf[ks] = *(const bf16x8*)(slab + swz<64>(l15, ks * 32 + q * 8));
#pragma unroll
        for (int qt = 0; qt < 4; ++qt) {
            bf16x8 t = *(const bf16x8*)(RA + swz<128>(qt * 16 + l15, colA));
            bf16x8 Qf = hi ? z8 : t;
            // softmax over ktok (rows of S^T) for fixed qtok = qt*16+l15.
            // BASELINE numerics: scale 0.25 (exact pow2), fp32 normalize
            // BEFORE bf16 quantization.  One S f32x4 live at a time.
            float P[4][4];
            float mx = -1e30f;
#pragma unroll
            for (int kt = 0; kt < 4; ++kt) {
                f32x4 S = MFMA16(Kf[kt], Qf, fzero);
#pragma unroll
                for (int r = 0; r < 4; ++r) {
                    const float sv = S[r] * 0.25f;  // HD^-0.5
                    P[kt][r] = sv;
                    mx = fmaxf(mx, sv);
                }
            }
            mx = fmaxf(mx, __shfl_xor(mx, 16));
            mx = fmaxf(mx, __shfl_xor(mx, 32));
            float lsum = 0.f;
#pragma unroll
            for (int kt = 0; kt < 4; ++kt)
#pragma unroll
                for (int r = 0; r < 4; ++r) {
                    const float e = __builtin_amdgcn_exp2f((P[kt][r] - mx) * 1.4426950408889634f);
                    P[kt][r] = e;
                    lsum += e;
                }
            lsum += __shfl_xor(lsum, 16);
            lsum += __shfl_xor(lsum, 32);
            const float inv = __builtin_amdgcn_rcpf(lsum);
            // normalized P -> slab as [qtok][ktok] bf16
#pragma unroll
            for (int kt = 0; kt < 4; ++kt) {
                f32x4 e4;
#pragma unroll
                for (int r = 0; r < 4; ++r) e4[r] = P[kt][r] * inv;
                st4(slab + swz<64>(l15, kt * 16 + q * 4), e4);
            }
            // O^T = V^T . P^T ; B-frag of P^T == row-contig bf16x8 of P slab
            f32x4 O = fzero;
#pragma unroll
            for (int ks = 0; ks < 2; ++ks) {
                bf16x8 Bf = *(const bf16x8*)(slab + swz<64>(l15, ks * 32 + q * 8));
                O = MFMA16(Vf[ks], Bf, O);
            }
            st4(RA + swz<128>(qt * 16 + l15, w * 16 + q * 4), O);  // over Q rows qt
        }
    }
    __syncthreads();

    // -------- stage 5: x2 += (O . w_proj)^T + b_proj; x2_bf16 -> RB ---------
    {
        f32x4 acc[4];
#pragma unroll
        for (int tt = 0; tt < 4; ++tt) acc[tt] = fzero;
#pragma unroll
        for (int ks = 0; ks < 4; ++ks) {
            bf16x8 afr = *(const bf16x8*)(wp + OFF_PROJ + ((w * 4 + ks) * 64 + lane) * 8);
#pragma unroll
            for (int tt = 0; tt < 4; ++tt) {
                bf16x8 bfr = *(const bf16x8*)(RA + swz<128>(tt * 16 + l15, ks * 32 + q * 8));
                acc[tt] = MFMA16(afr, bfr, acc[tt]);
            }
        }
        const f32x4 bias = *(const f32x4*)(b_proj + w * 16 + q * 4);
#pragma unroll
        for (int tt = 0; tt < 4; ++tt) {
#pragma unroll
            for (int r = 0; r < 4; ++r) x2[tt][r] += acc[tt][r] + bias[r];
            st4(RB + swz<128>(tt * 16 + l15, w * 16 + q * 4), x2[tt]);
        }
    }
    __syncthreads();

    // -------- stage 6: n2 = LN(x2)*g2+b2 : RB -> RA -------------------------
    ln_rows(RB, RA, g2, b2, tid);
    __syncthreads();

    // -------- stage 7: hidden = gelu(w_m1^T . n2^T + b_m1) (tt-outer) -------
    // hidden (64x256): cols 0:128 -> RB (waves 0-3), cols 128:256 -> RC
    // (waves 4-7).  Reads RA only, writes RB/RC only -> no mid barrier.
    {
#pragma unroll
        for (int tt = 0; tt < 4; ++tt) {
            bf16x8 Bfr[4];
#pragma unroll
            for (int ks = 0; ks < 4; ++ks)
                Bfr[ks] = *(const bf16x8*)(RA + swz<128>(tt * 16 + l15, ks * 32 + q * 8));
#pragma unroll
            for (int half = 0; half < 2; ++half) {
                const int mt = w * 2 + half;  // 0..15; mt<8 -> RB, else RC
                f32x4 acc = fzero;
#pragma unroll
                for (int ks = 0; ks < 4; ++ks) {
                    bf16x8 afr = *(const bf16x8*)(wp + OFF_M1 + ((mt * 4 + ks) * 64 + lane) * 8);
                    acc = MFMA16(afr, Bfr[ks], acc);
                }
                const f32x4 bias = *(const f32x4*)(b_m1 + mt * 16 + q * 4);
                f32x4 gl;
#pragma unroll
                for (int r = 0; r < 4; ++r) gl[r] = gelu_f(acc[r] + bias[r]);
                bf16* const dst = (mt < 8) ? RB : RC;
                st4(dst + swz<128>(tt * 16 + l15, (mt & 7) * 16 + q * 4), gl);
            }
        }
    }
    __syncthreads();

    // -------- stage 8: x2 += (hidden . w_m2)^T + b_m2; x2_bf16 -> RA --------
    {
        f32x4 acc[4];
#pragma unroll
        for (int tt = 0; tt < 4; ++tt) acc[tt] = fzero;
#pragma unroll
        for (int ks = 0; ks < 8; ++ks) {
            bf16x8 afr = *(const bf16x8*)(wp + OFF_M2 + ((w * 8 + ks) * 64 + lane) * 8);
            const bf16* const srcH = (ks < 4) ? RB : RC;
            const int colb = (ks & 3) * 32 + q * 8;
#pragma unroll
            for (int tt = 0; tt < 4; ++tt) {
                bf16x8 bfr = *(const bf16x8*)(srcH + swz<128>(tt * 16 + l15, colb));
                acc[tt] = MFMA16(afr, bfr, acc[tt]);
            }
        }
        const f32x4 bias = *(const f32x4*)(b_m2 + w * 16 + q * 4);
#pragma unroll
        for (int tt = 0; tt < 4; ++tt) {
#pragma unroll
            for (int r = 0; r < 4; ++r) x2[tt][r] += acc[tt][r] + bias[r];
            st4(RA + swz<128>(tt * 16 + l15, w * 16 + q * 4), x2[tt]);
        }
    }
    __syncthreads();

    // -------- stage 9: out^T = w_post^T . x2^T + b_post (fp32, dwordx4) -----
    // Wave w owns token tile tt = w>>1 and ct pair (w&1)*2 + {0,1} -> each
    // wave writes 128 contiguous bytes per token row (was 64 B scattered
    // between waves -> 4x write inflation).
    {
        const int tt  = w >> 1;        // token tile 0..3
        const int ct0 = (w & 1) * 2;   // out-channel tiles ct0, ct0+1
        f32x4 acc[2];
#pragma unroll
        for (int rr = 0; rr < 2; ++rr) acc[rr] = fzero;
#pragma unroll
        for (int ks = 0; ks < 4; ++ks) {
            bf16x8 bfr = *(const bf16x8*)(RA + swz<128>(tt * 16 + l15, ks * 32 + q * 8));
#pragma unroll
            for (int rr = 0; rr < 2; ++rr) {
                bf16x8 afr = *(const bf16x8*)(wp + OFF_POST + (((ct0 + rr) * 4 + ks) * 64 + lane) * 8);
                acc[rr] = MFMA16(afr, bfr, acc[rr]);
            }
        }
#pragma unroll
        for (int rr = 0; rr < 2; ++rr) {
            const f32x4 bias = *(const f32x4*)(b_post + (ct0 + rr) * 16 + q * 4);
            f32x4 v = acc[rr] + bias;
            *(f32x4*)(out + (base + tt * 16 + l15) * 64 + (ct0 + rr) * 16 + q * 4) = v;
        }
    }
}

extern "C" void kernel_launch(void* const* d_in, const int* in_sizes, int n_in,
                              void* d_out, int out_size, void* d_ws, size_t ws_size,
                              hipStream_t stream) {
    const float* feats  = (const float*)d_in[0];
    const float* w_pre  = (const float*)d_in[1];
    const float* b_pre  = (const float*)d_in[2];
    const float* g1     = (const float*)d_in[3];
    const float* b1     = (const float*)d_in[4];
    const float* w_qkv  = (const float*)d_in[5];
    const float* b_qkv  = (const float*)d_in[6];
    const float* w_proj = (const float*)d_in[7];
    const float* b_proj = (const float*)d_in[8];
    const float* g2     = (const float*)d_in[9];
    const float* b2     = (const float*)d_in[10];
    const float* w_m1   = (const float*)d_in[11];
    const float* b_m1   = (const float*)d_in[12];
    const float* w_m2   = (const float*)d_in[13];
    const float* b_m2   = (const float*)d_in[14];
    const float* w_post = (const float*)d_in[15];
    const float* b_post = (const float*)d_in[16];

    bf16* wp = (bf16*)d_ws;  // 288 KB of packed bf16 W^T A-fragments

    pack_all<<<288, 64, 0, stream>>>(w_pre, w_qkv, w_proj, w_m1, w_m2, w_post, wp);

    fused_block_kernel<<<8192, 512, 0, stream>>>(
        feats, wp, b_pre, g1, b1, b_qkv, b_proj, g2, b2, b_m1, b_m2, b_post,
        (float*)d_out);
}

// Round 6
// 802.672 us; speedup vs baseline: 1.0247x; 1.0247x over previous
//
#include <hip/hip_runtime.h>
#include <hip/hip_bf16.h>
#include <math.h>

// ---------------------------------------------------------------------------
// Fully fused transformer block, TRANSPOSED-GEMM formulation.
// One workgroup (512 thr = 8 waves) per 64-token window; 8192 windows.
// Round 6 (base = round 4, 497us verified; occupancy lever abandoned after
// r3/r5 both spilled under launch_bounds(512,6) -> bounds stays (512,4)):
//  * stage 0+1 FUSED: feats B-fragments read straight from global (fully
//    coalesced 2KB/inst; waves 2..8 hit L2) -> stage-0 LDS round-trip and
//    one barrier removed, HBM latency overlapped with stage-1 MFMAs.
//  * max-free softmax: e^s normalizes identically to e^(s-mx); |arg|<=~14
//    << 88 so no overflow. Kills 34 VALU/qt and the all-kt max dependency.
//  * stage 9 remap (r5, arithmetic-neutral): wave owns (tt, ct-pair) ->
//    128B contiguous per token row (write inflation 4x -> ~2x).
//  KEPT from r4: LDS 48KB 3-region overlay; P^T via LDS round-trip through
//  the dead V slab; V frags hoisted; baseline softmax scale/normalize order.
// Layouts (guide §3, HW-verified): A[m=lane&15][k=quad*8+j],
// B[k=quad*8+j][n=lane&15], D[row=quad*4+reg][col=lane&15].
// ---------------------------------------------------------------------------

typedef __bf16 bf16;
typedef __bf16 bf16x8 __attribute__((ext_vector_type(8)));
typedef __bf16 bf16x4 __attribute__((ext_vector_type(4)));
typedef float  f32x4  __attribute__((ext_vector_type(4)));

#define MFMA16(a, b, c) __builtin_amdgcn_mfma_f32_16x16x32_bf16((a), (b), (c), 0, 0, 0)

// packed-weight element offsets inside d_ws (bf16 elements)
constexpr int OFF_PRE  = 0;       // w_pre  64x128 : KT=2, MT=8  -> 16 tiles
constexpr int OFF_QKV  = 8192;    // w_qkv 128x384 : KT=4, MT=24 -> 96 tiles
constexpr int OFF_PROJ = 57344;   // w_proj128x128 : KT=4, MT=8  -> 32 tiles
constexpr int OFF_M1   = 73728;   // w_m1  128x256 : KT=4, MT=16 -> 64 tiles
constexpr int OFF_M2   = 106496;  // w_m2  256x128 : KT=8, MT=8  -> 64 tiles
constexpr int OFF_POST = 139264;  // w_post128x64  : KT=4, MT=4  -> 16 tiles
// total 147456 bf16 = 288 KB in d_ws

// XOR-swizzled row-major layout (16B chunks XOR row) -> conflict-light
// ds_read_b128 / ds_write_b64 without padding.
template <int W>
__device__ __forceinline__ int swz(int row, int col) {
    constexpr int CH = W >> 3;
    constexpr int M  = (CH - 1) < 15 ? (CH - 1) : 15;
    const int c = (col >> 3) ^ (row & M);
    return row * W + c * 8 + (col & 7);
}

__device__ __forceinline__ bf16x8 zero8() {
    bf16x8 z;
#pragma unroll
    for (int j = 0; j < 8; ++j) z[j] = (bf16)0.0f;
    return z;
}

// store 4 fp32 as 4 consecutive bf16 (8B). col base is 4-aligned -> stays
// inside one 8-elem swizzle chunk -> single ds_write_b64.
__device__ __forceinline__ void st4(bf16* p, const f32x4 v) {
    bf16x4 o;
#pragma unroll
    for (int r = 0; r < 4; ++r) o[r] = (bf16)v[r];
    *(bf16x4*)p = o;
}

// fast gelu: x * sigmoid(2u), u = 0.79788456(x + 0.044715 x^3)
__device__ __forceinline__ float gelu_f(float x) {
    const float u = 0.79788456f * x * (1.0f + 0.044715f * x * x);
    const float e = __builtin_amdgcn_exp2f(u * 2.8853900817779268f);  // e^(2u)
    return x - x * __builtin_amdgcn_rcpf(e + 1.0f);  // robust at e->inf
}

// pack two float4 (8 consecutive fp32) into a bf16x8 B-fragment
__device__ __forceinline__ bf16x8 pack8(const float4 a, const float4 b) {
    bf16x8 v;
    v[0] = (bf16)a.x; v[1] = (bf16)a.y; v[2] = (bf16)a.z; v[3] = (bf16)a.w;
    v[4] = (bf16)b.x; v[5] = (bf16)b.y; v[6] = (bf16)b.z; v[7] = (bf16)b.w;
    return v;
}

// ---------------------------------------------------------------------------
// Weight packer: fp32 W[K][N] -> A-frag tiles of W^T (== B-frag tiles of W).
// Tile (mt,kt): lane l, frag[j] = W[kt*32 + (l>>4)*8 + j][mt*16 + (l&15)].
// All six weights in ONE kernel (288 blocks) to avoid 6 launch latencies.
// ---------------------------------------------------------------------------
__global__ void pack_all(const float* __restrict__ w_pre,
                         const float* __restrict__ w_qkv,
                         const float* __restrict__ w_proj,
                         const float* __restrict__ w_m1,
                         const float* __restrict__ w_m2,
                         const float* __restrict__ w_post,
                         bf16* __restrict__ dst) {
    const int t = blockIdx.x;
    const float* src;
    int Ncol, KT, off, t0;
    if (t < 16)       { src = w_pre;  Ncol = 128; KT = 2; off = OFF_PRE;  t0 = 0; }
    else if (t < 112) { src = w_qkv;  Ncol = 384; KT = 4; off = OFF_QKV;  t0 = 16; }
    else if (t < 144) { src = w_proj; Ncol = 128; KT = 4; off = OFF_PROJ; t0 = 112; }
    else if (t < 208) { src = w_m1;   Ncol = 256; KT = 4; off = OFF_M1;   t0 = 144; }
    else if (t < 272) { src = w_m2;   Ncol = 128; KT = 8; off = OFF_M2;   t0 = 208; }
    else              { src = w_post; Ncol = 64;  KT = 4; off = OFF_POST; t0 = 272; }
    const int tile = t - t0;
    const int lane = threadIdx.x;
    const int mt = tile / KT, kt = tile - mt * KT;
    const int n  = mt * 16 + (lane & 15);
    const int k0 = kt * 32 + (lane >> 4) * 8;
    bf16x8 v;
#pragma unroll
    for (int j = 0; j < 8; ++j) v[j] = (bf16)src[(k0 + j) * Ncol + n];
    // NOTE: destination MUST include the per-weight region offset `off`.
    *(bf16x8*)(dst + off + ((long)(tile * 64 + lane)) * 8) = v;
}

// LayerNorm over 128 channels: 8 lanes per row, shuffle-reduce, bf16 out.
__device__ __forceinline__ void ln_rows(const bf16* __restrict__ in,
                                        bf16* __restrict__ outb,
                                        const float* __restrict__ g,
                                        const float* __restrict__ b, int tid) {
    const int row = tid >> 3, sub = tid & 7;
    bf16x8 c0 = *(const bf16x8*)(in + swz<128>(row, sub * 16));
    bf16x8 c1 = *(const bf16x8*)(in + swz<128>(row, sub * 16 + 8));
    float v[16];
#pragma unroll
    for (int j = 0; j < 8; ++j) { v[j] = (float)c0[j]; v[8 + j] = (float)c1[j]; }
    float s = 0.f, ss = 0.f;
#pragma unroll
    for (int j = 0; j < 16; ++j) { s += v[j]; ss += v[j] * v[j]; }
#pragma unroll
    for (int m = 1; m <= 4; m <<= 1) {
        s += __shfl_xor(s, m);
        ss += __shfl_xor(ss, m);
    }
    const float mu   = s * (1.0f / 128.0f);
    const float rstd = __builtin_amdgcn_rsqf(ss * (1.0f / 128.0f) - mu * mu + 1e-5f);
    bf16x8 o0, o1;
#pragma unroll
    for (int j = 0; j < 8; ++j) {
        o0[j] = (bf16)((v[j] - mu) * rstd * g[sub * 16 + j] + b[sub * 16 + j]);
        o1[j] = (bf16)((v[8 + j] - mu) * rstd * g[sub * 16 + 8 + j] + b[sub * 16 + 8 + j]);
    }
    *(bf16x8*)(outb + swz<128>(row, sub * 16)) = o0;
    *(bf16x8*)(outb + swz<128>(row, sub * 16 + 8)) = o1;
}

__global__ __launch_bounds__(512, 4)
void fused_block_kernel(const float* __restrict__ feats,
                        const bf16* __restrict__ wp,
                        const float* __restrict__ b_pre,
                        const float* __restrict__ g1, const float* __restrict__ b1,
                        const float* __restrict__ b_qkv,
                        const float* __restrict__ b_proj,
                        const float* __restrict__ g2, const float* __restrict__ b2,
                        const float* __restrict__ b_m1,
                        const float* __restrict__ b_m2,
                        const float* __restrict__ b_post,
                        float* __restrict__ out) {
    // 48 KB static LDS, three 16 KB regions, time-multiplexed:
    //  RA: n1 -> Q -> O -> n2 -> x2_bf16(post input)
    //  RB: x2_bf16(LN1 in) -> K -> x2_bf16(LN2 in) -> hidden[:,0:128]
    //  RC: per-wave slabs (V^T then P, 1024 elems each) -> hidden[:,128:256]
    // Lifetime rules: a region is overwritten only after (a) an all-wave
    // barrier past its last cross-wave read, or (b) it is same-wave-private.
    __shared__ __align__(16) bf16 RA[64 * 128];
    __shared__ __align__(16) bf16 RB[64 * 128];
    __shared__ __align__(16) bf16 RC[64 * 128];

    const int tid  = threadIdx.x;
    const int w    = tid >> 6;   // wave 0..7 == head / out-channel-tile owner
    const int lane = tid & 63;
    const int q    = lane >> 4;  // quad
    const int l15  = lane & 15;
    const long base = (long)blockIdx.x * 64;
    const f32x4 fzero = {0.f, 0.f, 0.f, 0.f};

    // residual stream in regs: x2[tt][r] = x2[token tt*16+l15][ch w*16+q*4+r]
    f32x4 x2[4];

    // -------- stage 1: x2^T = w_pre^T . feats^T + b_pre; x2_bf16 -> RB ------
    // feats B-frags read DIRECTLY from global (no LDS staging, no barrier):
    // lane (q,l15), frag j = feats[base + tt*16 + l15][ks*32 + q*8 + j]
    // -> two float4 per frag; a wave covers complete 256B rows (coalesced).
    {
        bf16x8 bfr[2][4];
#pragma unroll
        for (int ks = 0; ks < 2; ++ks)
#pragma unroll
            for (int tt = 0; tt < 4; ++tt) {
                const float* fp = feats + (base + tt * 16 + l15) * 64 + ks * 32 + q * 8;
                float4 a = *(const float4*)fp;
                float4 b = *(const float4*)(fp + 4);
                bfr[ks][tt] = pack8(a, b);
            }
        f32x4 acc[4];
#pragma unroll
        for (int tt = 0; tt < 4; ++tt) acc[tt] = fzero;
#pragma unroll
        for (int ks = 0; ks < 2; ++ks) {
            bf16x8 afr = *(const bf16x8*)(wp + OFF_PRE + ((w * 2 + ks) * 64 + lane) * 8);
#pragma unroll
            for (int tt = 0; tt < 4; ++tt)
                acc[tt] = MFMA16(afr, bfr[ks][tt], acc[tt]);
        }
        const f32x4 bias = *(const f32x4*)(b_pre + w * 16 + q * 4);
#pragma unroll
        for (int tt = 0; tt < 4; ++tt) {
#pragma unroll
            for (int r = 0; r < 4; ++r) x2[tt][r] = acc[tt][r] + bias[r];
            st4(RB + swz<128>(tt * 16 + l15, w * 16 + q * 4), x2[tt]);
        }
    }
    __syncthreads();

    // -------- stage 2: n1 = LN(x2)*g1+b1 : RB -> RA -------------------------
    ln_rows(RB, RA, g1, b1, tid);
    __syncthreads();

    // -------- stage 3: qkv^T = w_qkv^T . n1^T + b_qkv -----------------------
    // n1 consumed into regs first, then RA is reused for Q (barrier between).
    // wave w: Q head w -> RA (cols 16w..), K head w -> RB (cols 16w..),
    // V head w -> RC slab w, transposed [ch][tok].
    {
        bf16x8 Bfr[4][4];
#pragma unroll
        for (int ks = 0; ks < 4; ++ks)
#pragma unroll
            for (int tt = 0; tt < 4; ++tt)
                Bfr[ks][tt] = *(const bf16x8*)(RA + swz<128>(tt * 16 + l15, ks * 32 + q * 8));
        __syncthreads();  // all waves done reading n1; RA writable
#pragma unroll
        for (int part = 0; part < 3; ++part) {
            const int mt = part * 8 + w;
            f32x4 acc[4];
#pragma unroll
            for (int tt = 0; tt < 4; ++tt) acc[tt] = fzero;
#pragma unroll
            for (int ks = 0; ks < 4; ++ks) {
                bf16x8 afr = *(const bf16x8*)(wp + OFF_QKV + ((mt * 4 + ks) * 64 + lane) * 8);
#pragma unroll
                for (int tt = 0; tt < 4; ++tt) acc[tt] = MFMA16(afr, Bfr[ks][tt], acc[tt]);
            }
            const f32x4 bias = *(const f32x4*)(b_qkv + mt * 16 + q * 4);
            if (part == 0) {
#pragma unroll
                for (int tt = 0; tt < 4; ++tt)
                    st4(RA + swz<128>(tt * 16 + l15, w * 16 + q * 4), acc[tt] + bias);
            } else if (part == 1) {
#pragma unroll
                for (int tt = 0; tt < 4; ++tt)
                    st4(RB + swz<128>(tt * 16 + l15, w * 16 + q * 4), acc[tt] + bias);
            } else {
#pragma unroll
                for (int tt = 0; tt < 4; ++tt)
#pragma unroll
                    for (int r = 0; r < 4; ++r)
                        RC[w * 1024 + swz<64>(q * 4 + r, tt * 16 + l15)] =
                            (bf16)(acc[tt][r] + bias[r]);
            }
        }
    }
    __syncthreads();  // conservative (r1's removal correlated with a flaky fail)

    // -------- stage 4: attention (wave w = head w), S^T = K.Q^T -------------
    {
        const int colA = w * 16 + (q & 1) * 8;  // HD=16: quads>=2 zero-padded
        const bool hi = (q >= 2);
        const bf16x8 z8 = zero8();
        bf16* const slab = RC + w * 1024;  // [16][64] swz<64>: V^T, then P
        bf16x8 Kf[4];
#pragma unroll
        for (int kt = 0; kt < 4; ++kt) {
            bf16x8 t = *(const bf16x8*)(RB + swz<128>(kt * 16 + l15, colA));
            Kf[kt] = hi ? z8 : t;
        }
        // V frags are qt-independent: load once, then the slab is free for P.
        bf16x8 Vf[2];
#pragma unroll
        for (int ks = 0; ks < 2; ++ks)
            Vf[ks] = *(const bf16x8*)(slab + swz<64>(l15, ks * 32 + q * 8));
#pragma unroll
        for (int qt = 0; qt < 4; ++qt) {
            bf16x8 t = *(const bf16x8*)(RA + swz<128>(qt * 16 + l15, colA));
            bf16x8 Qf = hi ? z8 : t;
            // MAX-FREE softmax over ktok for fixed qtok = qt*16+l15:
            // e^s normalizes identically to e^(s-mx); |s*0.25*log2e| <= ~14
            // << 88, no overflow.  exp of S[kt] issues as soon as its MFMA
            // lands (no all-kt max dependency).  fp32 normalize BEFORE bf16
            // quantization (baseline numerics otherwise).
            float P[4][4];
            float lsum = 0.f;
#pragma unroll
            for (int kt = 0; kt < 4; ++kt) {
                f32x4 S = MFMA16(Kf[kt], Qf, fzero);
#pragma unroll
                for (int r = 0; r < 4; ++r) {
                    const float sv = S[r] * 0.25f;  // HD^-0.5
                    const float e = __builtin_amdgcn_exp2f(sv * 1.4426950408889634f);
                    P[kt][r] = e;
                    lsum += e;
                }
            }
            lsum += __shfl_xor(lsum, 16);
            lsum += __shfl_xor(lsum, 32);
            const float inv = __builtin_amdgcn_rcpf(lsum);
            // normalized P -> slab as [qtok][ktok] bf16
#pragma unroll
            for (int kt = 0; kt < 4; ++kt) {
                f32x4 e4;
#pragma unroll
                for (int r = 0; r < 4; ++r) e4[r] = P[kt][r] * inv;
                st4(slab + swz<64>(l15, kt * 16 + q * 4), e4);
            }
            // O^T = V^T . P^T ; B-frag of P^T == row-contig bf16x8 of P slab
            f32x4 O = fzero;
#pragma unroll
            for (int ks = 0; ks < 2; ++ks) {
                bf16x8 Bf = *(const bf16x8*)(slab + swz<64>(l15, ks * 32 + q * 8));
                O = MFMA16(Vf[ks], Bf, O);
            }
            st4(RA + swz<128>(qt * 16 + l15, w * 16 + q * 4), O);  // over Q rows qt
        }
    }
    __syncthreads();

    // -------- stage 5: x2 += (O . w_proj)^T + b_proj; x2_bf16 -> RB ---------
    {
        f32x4 acc[4];
#pragma unroll
        for (int tt = 0; tt < 4; ++tt) acc[tt] = fzero;
#pragma unroll
        for (int ks = 0; ks < 4; ++ks) {
            bf16x8 afr = *(const bf16x8*)(wp + OFF_PROJ + ((w * 4 + ks) * 64 + lane) * 8);
#pragma unroll
            for (int tt = 0; tt < 4; ++tt) {
                bf16x8 bfr = *(const bf16x8*)(RA + swz<128>(tt * 16 + l15, ks * 32 + q * 8));
                acc[tt] = MFMA16(afr, bfr, acc[tt]);
            }
        }
        const f32x4 bias = *(const f32x4*)(b_proj + w * 16 + q * 4);
#pragma unroll
        for (int tt = 0; tt < 4; ++tt) {
#pragma unroll
            for (int r = 0; r < 4; ++r) x2[tt][r] += acc[tt][r] + bias[r];
            st4(RB + swz<128>(tt * 16 + l15, w * 16 + q * 4), x2[tt]);
        }
    }
    __syncthreads();

    // -------- stage 6: n2 = LN(x2)*g2+b2 : RB -> RA -------------------------
    ln_rows(RB, RA, g2, b2, tid);
    __syncthreads();

    // -------- stage 7: hidden = gelu(w_m1^T . n2^T + b_m1) ------------------
    // n2 consumed into regs; hidden (64x256) split: cols 0:128 -> RB,
    // cols 128:256 -> RC. Writes don't touch RA, so no mid-stage barrier.
    {
        bf16x8 Bfr[4][4];
#pragma unroll
        for (int ks = 0; ks < 4; ++ks)
#pragma unroll
            for (int tt = 0; tt < 4; ++tt)
                Bfr[ks][tt] = *(const bf16x8*)(RA + swz<128>(tt * 16 + l15, ks * 32 + q * 8));
#pragma unroll
        for (int half = 0; half < 2; ++half) {
            const int mt = w * 2 + half;  // 0..15; mt<8 -> RB, else RC
            f32x4 acc[4];
#pragma unroll
            for (int tt = 0; tt < 4; ++tt) acc[tt] = fzero;
#pragma unroll
            for (int ks = 0; ks < 4; ++ks) {
                bf16x8 afr = *(const bf16x8*)(wp + OFF_M1 + ((mt * 4 + ks) * 64 + lane) * 8);
#pragma unroll
                for (int tt = 0; tt < 4; ++tt) acc[tt] = MFMA16(afr, Bfr[ks][tt], acc[tt]);
            }
            const f32x4 bias = *(const f32x4*)(b_m1 + mt * 16 + q * 4);
            bf16* const dst = (mt < 8) ? RB : RC;
            const int colb  = (mt & 7) * 16 + q * 4;
#pragma unroll
            for (int tt = 0; tt < 4; ++tt) {
                f32x4 gl;
#pragma unroll
                for (int r = 0; r < 4; ++r) gl[r] = gelu_f(acc[tt][r] + bias[r]);
                st4(dst + swz<128>(tt * 16 + l15, colb), gl);
            }
        }
    }
    __syncthreads();

    // -------- stage 8: x2 += (hidden . w_m2)^T + b_m2; x2_bf16 -> RA --------
    {
        f32x4 acc[4];
#pragma unroll
        for (int tt = 0; tt < 4; ++tt) acc[tt] = fzero;
#pragma unroll
        for (int ks = 0; ks < 8; ++ks) {
            bf16x8 afr = *(const bf16x8*)(wp + OFF_M2 + ((w * 8 + ks) * 64 + lane) * 8);
            const bf16* const srcH = (ks < 4) ? RB : RC;
            const int colb = (ks & 3) * 32 + q * 8;
#pragma unroll
            for (int tt = 0; tt < 4; ++tt) {
                bf16x8 bfr = *(const bf16x8*)(srcH + swz<128>(tt * 16 + l15, colb));
                acc[tt] = MFMA16(afr, bfr, acc[tt]);
            }
        }
        const f32x4 bias = *(const f32x4*)(b_m2 + w * 16 + q * 4);
#pragma unroll
        for (int tt = 0; tt < 4; ++tt) {
#pragma unroll
            for (int r = 0; r < 4; ++r) x2[tt][r] += acc[tt][r] + bias[r];
            st4(RA + swz<128>(tt * 16 + l15, w * 16 + q * 4), x2[tt]);
        }
    }
    __syncthreads();

    // -------- stage 9: out^T = w_post^T . x2^T + b_post (fp32, dwordx4) -----
    // Wave w owns token tile tt = w>>1 and ct pair (w&1)*2 + {0,1} -> each
    // wave writes 128 contiguous bytes per token row.
    {
        const int tt  = w >> 1;        // token tile 0..3
        const int ct0 = (w & 1) * 2;   // out-channel tiles ct0, ct0+1
        f32x4 acc[2];
#pragma unroll
        for (int rr = 0; rr < 2; ++rr) acc[rr] = fzero;
#pragma unroll
        for (int ks = 0; ks < 4; ++ks) {
            bf16x8 bfr = *(const bf16x8*)(RA + swz<128>(tt * 16 + l15, ks * 32 + q * 8));
#pragma unroll
            for (int rr = 0; rr < 2; ++rr) {
                bf16x8 afr = *(const bf16x8*)(wp + OFF_POST + (((ct0 + rr) * 4 + ks) * 64 + lane) * 8);
                acc[rr] = MFMA16(afr, bfr, acc[rr]);
            }
        }
#pragma unroll
        for (int rr = 0; rr < 2; ++rr) {
            const f32x4 bias = *(const f32x4*)(b_post + (ct0 + rr) * 16 + q * 4);
            f32x4 v = acc[rr] + bias;
            *(f32x4*)(out + (base + tt * 16 + l15) * 64 + (ct0 + rr) * 16 + q * 4) = v;
        }
    }
}

extern "C" void kernel_launch(void* const* d_in, const int* in_sizes, int n_in,
                              void* d_out, int out_size, void* d_ws, size_t ws_size,
                              hipStream_t stream) {
    const float* feats  = (const float*)d_in[0];
    const float* w_pre  = (const float*)d_in[1];
    const float* b_pre  = (const float*)d_in[2];
    const float* g1     = (const float*)d_in[3];
    const float* b1     = (const float*)d_in[4];
    const float* w_qkv  = (const float*)d_in[5];
    const float* b_qkv  = (const float*)d_in[6];
    const float* w_proj = (const float*)d_in[7];
    const float* b_proj = (const float*)d_in[8];
    const float* g2     = (const float*)d_in[9];
    const float* b2     = (const float*)d_in[10];
    const float* w_m1   = (const float*)d_in[11];
    const float* b_m1   = (const float*)d_in[12];
    const float* w_m2   = (const float*)d_in[13];
    const float* b_m2   = (const float*)d_in[14];
    const float* w_post = (const float*)d_in[15];
    const float* b_post = (const float*)d_in[16];

    bf16* wp = (bf16*)d_ws;  // 288 KB of packed bf16 W^T A-fragments

    pack_all<<<288, 64, 0, stream>>>(w_pre, w_qkv, w_proj, w_m1, w_m2, w_post, wp);

    fused_block_kernel<<<8192, 512, 0, stream>>>(
        feats, wp, b_pre, g1, b1, b_qkv, b_proj, g2, b2, b_m1, b_m2, b_post,
        (float*)d_out);
}

// Round 7
// 670.550 us; speedup vs baseline: 1.2266x; 1.1970x over previous
//
#include <hip/hip_runtime.h>
#include <hip/hip_bf16.h>
#include <math.h>

// ---------------------------------------------------------------------------
// Fully fused transformer block, TRANSPOSED-GEMM formulation.
// One workgroup (512 thr = 8 waves) per 64-token window; 8192 windows.
// Round 7 (base = round 4, 497us verified):
//  * REVERTED r6's feats-direct fusion (FETCH +180MB, front-of-block latency
//    exposure -> dur +176us) -> stage-0 LDS staging restored.
//  * REVERTED r6's stage-9 remap (WRITE 519->671MB measured) -> r4 mapping.
//  * KEPT max-free softmax (e^s normalizes identically to e^(s-mx);
//    |s*0.25*log2e|<=~14 << 88; passed r6 at absmax 0.078).
//  * NEW: stage3->stage4 barrier REMOVED. Verified same-wave-only data flow:
//    wave w writes complete Q panel (RA cols 16w.., all 64 rows), K panel
//    (RB cols 16w..), V slab (RC slab w); stage 4 of wave w reads exactly
//    those regions. Same-wave LDS ops are program-ordered -> no sync needed.
//    (r1's failure is attributed to its softmax numerics; r2 exonerated the
//    structural changes with the barrier present.)
//  Barriers per block: 9 -> 8; stages 3+4 now one barrier-free region
//  (~72 MFMAs + softmax), the block's biggest contiguous work chunk.
// Layouts (guide §3, HW-verified): A[m=lane&15][k=quad*8+j],
// B[k=quad*8+j][n=lane&15], D[row=quad*4+reg][col=lane&15].
// ---------------------------------------------------------------------------

typedef __bf16 bf16;
typedef __bf16 bf16x8 __attribute__((ext_vector_type(8)));
typedef __bf16 bf16x4 __attribute__((ext_vector_type(4)));
typedef float  f32x4  __attribute__((ext_vector_type(4)));

#define MFMA16(a, b, c) __builtin_amdgcn_mfma_f32_16x16x32_bf16((a), (b), (c), 0, 0, 0)

// packed-weight element offsets inside d_ws (bf16 elements)
constexpr int OFF_PRE  = 0;       // w_pre  64x128 : KT=2, MT=8  -> 16 tiles
constexpr int OFF_QKV  = 8192;    // w_qkv 128x384 : KT=4, MT=24 -> 96 tiles
constexpr int OFF_PROJ = 57344;   // w_proj128x128 : KT=4, MT=8  -> 32 tiles
constexpr int OFF_M1   = 73728;   // w_m1  128x256 : KT=4, MT=16 -> 64 tiles
constexpr int OFF_M2   = 106496;  // w_m2  256x128 : KT=8, MT=8  -> 64 tiles
constexpr int OFF_POST = 139264;  // w_post128x64  : KT=4, MT=4  -> 16 tiles
// total 147456 bf16 = 288 KB in d_ws

// XOR-swizzled row-major layout (16B chunks XOR row) -> conflict-light
// ds_read_b128 / ds_write_b64 without padding.
template <int W>
__device__ __forceinline__ int swz(int row, int col) {
    constexpr int CH = W >> 3;
    constexpr int M  = (CH - 1) < 15 ? (CH - 1) : 15;
    const int c = (col >> 3) ^ (row & M);
    return row * W + c * 8 + (col & 7);
}

__device__ __forceinline__ bf16x8 zero8() {
    bf16x8 z;
#pragma unroll
    for (int j = 0; j < 8; ++j) z[j] = (bf16)0.0f;
    return z;
}

// store 4 fp32 as 4 consecutive bf16 (8B). col base is 4-aligned -> stays
// inside one 8-elem swizzle chunk -> single ds_write_b64.
__device__ __forceinline__ void st4(bf16* p, const f32x4 v) {
    bf16x4 o;
#pragma unroll
    for (int r = 0; r < 4; ++r) o[r] = (bf16)v[r];
    *(bf16x4*)p = o;
}

// fast gelu: x * sigmoid(2u), u = 0.79788456(x + 0.044715 x^3)
__device__ __forceinline__ float gelu_f(float x) {
    const float u = 0.79788456f * x * (1.0f + 0.044715f * x * x);
    const float e = __builtin_amdgcn_exp2f(u * 2.8853900817779268f);  // e^(2u)
    return x - x * __builtin_amdgcn_rcpf(e + 1.0f);  // robust at e->inf
}

// ---------------------------------------------------------------------------
// Weight packer: fp32 W[K][N] -> A-frag tiles of W^T (== B-frag tiles of W).
// Tile (mt,kt): lane l, frag[j] = W[kt*32 + (l>>4)*8 + j][mt*16 + (l&15)].
// All six weights in ONE kernel (288 blocks) to avoid 6 launch latencies.
// ---------------------------------------------------------------------------
__global__ void pack_all(const float* __restrict__ w_pre,
                         const float* __restrict__ w_qkv,
                         const float* __restrict__ w_proj,
                         const float* __restrict__ w_m1,
                         const float* __restrict__ w_m2,
                         const float* __restrict__ w_post,
                         bf16* __restrict__ dst) {
    const int t = blockIdx.x;
    const float* src;
    int Ncol, KT, off, t0;
    if (t < 16)       { src = w_pre;  Ncol = 128; KT = 2; off = OFF_PRE;  t0 = 0; }
    else if (t < 112) { src = w_qkv;  Ncol = 384; KT = 4; off = OFF_QKV;  t0 = 16; }
    else if (t < 144) { src = w_proj; Ncol = 128; KT = 4; off = OFF_PROJ; t0 = 112; }
    else if (t < 208) { src = w_m1;   Ncol = 256; KT = 4; off = OFF_M1;   t0 = 144; }
    else if (t < 272) { src = w_m2;   Ncol = 128; KT = 8; off = OFF_M2;   t0 = 208; }
    else              { src = w_post; Ncol = 64;  KT = 4; off = OFF_POST; t0 = 272; }
    const int tile = t - t0;
    const int lane = threadIdx.x;
    const int mt = tile / KT, kt = tile - mt * KT;
    const int n  = mt * 16 + (lane & 15);
    const int k0 = kt * 32 + (lane >> 4) * 8;
    bf16x8 v;
#pragma unroll
    for (int j = 0; j < 8; ++j) v[j] = (bf16)src[(k0 + j) * Ncol + n];
    // NOTE: destination MUST include the per-weight region offset `off`.
    *(bf16x8*)(dst + off + ((long)(tile * 64 + lane)) * 8) = v;
}

// LayerNorm over 128 channels: 8 lanes per row, shuffle-reduce, bf16 out.
__device__ __forceinline__ void ln_rows(const bf16* __restrict__ in,
                                        bf16* __restrict__ outb,
                                        const float* __restrict__ g,
                                        const float* __restrict__ b, int tid) {
    const int row = tid >> 3, sub = tid & 7;
    bf16x8 c0 = *(const bf16x8*)(in + swz<128>(row, sub * 16));
    bf16x8 c1 = *(const bf16x8*)(in + swz<128>(row, sub * 16 + 8));
    float v[16];
#pragma unroll
    for (int j = 0; j < 8; ++j) { v[j] = (float)c0[j]; v[8 + j] = (float)c1[j]; }
    float s = 0.f, ss = 0.f;
#pragma unroll
    for (int j = 0; j < 16; ++j) { s += v[j]; ss += v[j] * v[j]; }
#pragma unroll
    for (int m = 1; m <= 4; m <<= 1) {
        s += __shfl_xor(s, m);
        ss += __shfl_xor(ss, m);
    }
    const float mu   = s * (1.0f / 128.0f);
    const float rstd = __builtin_amdgcn_rsqf(ss * (1.0f / 128.0f) - mu * mu + 1e-5f);
    bf16x8 o0, o1;
#pragma unroll
    for (int j = 0; j < 8; ++j) {
        o0[j] = (bf16)((v[j] - mu) * rstd * g[sub * 16 + j] + b[sub * 16 + j]);
        o1[j] = (bf16)((v[8 + j] - mu) * rstd * g[sub * 16 + 8 + j] + b[sub * 16 + 8 + j]);
    }
    *(bf16x8*)(outb + swz<128>(row, sub * 16)) = o0;
    *(bf16x8*)(outb + swz<128>(row, sub * 16 + 8)) = o1;
}

__global__ __launch_bounds__(512, 4)
void fused_block_kernel(const float* __restrict__ feats,
                        const bf16* __restrict__ wp,
                        const float* __restrict__ b_pre,
                        const float* __restrict__ g1, const float* __restrict__ b1,
                        const float* __restrict__ b_qkv,
                        const float* __restrict__ b_proj,
                        const float* __restrict__ g2, const float* __restrict__ b2,
                        const float* __restrict__ b_m1,
                        const float* __restrict__ b_m2,
                        const float* __restrict__ b_post,
                        float* __restrict__ out) {
    // 48 KB static LDS, three 16 KB regions, time-multiplexed:
    //  RA: feats(8KB, swz<64>) -> n1 -> Q -> O -> n2 -> x2_bf16(post input)
    //  RB: x2_bf16(LN1 in) -> K -> x2_bf16(LN2 in) -> hidden[:,0:128]
    //  RC: per-wave slabs (V^T then P, 1024 elems each) -> hidden[:,128:256]
    // Lifetime rules: a region is overwritten only after (a) an all-wave
    // barrier past its last cross-wave read, or (b) it is same-wave-private.
    __shared__ __align__(16) bf16 RA[64 * 128];
    __shared__ __align__(16) bf16 RB[64 * 128];
    __shared__ __align__(16) bf16 RC[64 * 128];

    const int tid  = threadIdx.x;
    const int w    = tid >> 6;   // wave 0..7 == head / out-channel-tile owner
    const int lane = tid & 63;
    const int q    = lane >> 4;  // quad
    const int l15  = lane & 15;
    const long base = (long)blockIdx.x * 64;
    const f32x4 fzero = {0.f, 0.f, 0.f, 0.f};

    // -------- stage 0: feats (64x64 fp32) -> RA bf16, swizzled --------------
    {
        const int row = tid >> 3, ch = tid & 7;
        const float* src = feats + (base + row) * 64 + ch * 8;
        float4 a = *(const float4*)src;
        float4 b = *(const float4*)(src + 4);
        bf16x8 v;
        v[0] = (bf16)a.x; v[1] = (bf16)a.y; v[2] = (bf16)a.z; v[3] = (bf16)a.w;
        v[4] = (bf16)b.x; v[5] = (bf16)b.y; v[6] = (bf16)b.z; v[7] = (bf16)b.w;
        *(bf16x8*)(RA + swz<64>(row, ch * 8)) = v;
    }
    __syncthreads();

    // residual stream in regs: x2[tt][r] = x2[token tt*16+l15][ch w*16+q*4+r]
    f32x4 x2[4];

    // -------- stage 1: x2^T = w_pre^T . feats^T + b_pre; x2_bf16 -> RB ------
    {
        f32x4 acc[4];
#pragma unroll
        for (int tt = 0; tt < 4; ++tt) acc[tt] = fzero;
#pragma unroll
        for (int ks = 0; ks < 2; ++ks) {
            bf16x8 afr = *(const bf16x8*)(wp + OFF_PRE + ((w * 2 + ks) * 64 + lane) * 8);
#pragma unroll
            for (int tt = 0; tt < 4; ++tt) {
                bf16x8 bfr = *(const bf16x8*)(RA + swz<64>(tt * 16 + l15, ks * 32 + q * 8));
                acc[tt] = MFMA16(afr, bfr, acc[tt]);
            }
        }
        const f32x4 bias = *(const f32x4*)(b_pre + w * 16 + q * 4);
#pragma unroll
        for (int tt = 0; tt < 4; ++tt) {
#pragma unroll
            for (int r = 0; r < 4; ++r) x2[tt][r] = acc[tt][r] + bias[r];
            st4(RB + swz<128>(tt * 16 + l15, w * 16 + q * 4), x2[tt]);
        }
    }
    __syncthreads();

    // -------- stage 2: n1 = LN(x2)*g1+b1 : RB -> RA -------------------------
    ln_rows(RB, RA, g1, b1, tid);
    __syncthreads();

    // -------- stage 3: qkv^T = w_qkv^T . n1^T + b_qkv -----------------------
    // n1 consumed into regs first, then RA is reused for Q (barrier between).
    // wave w: Q head w -> RA (cols 16w..), K head w -> RB (cols 16w..),
    // V head w -> RC slab w, transposed [ch][tok].  All panels are complete
    // per wave (all 64 rows x its 16 cols) and consumed ONLY by wave w.
    {
        bf16x8 Bfr[4][4];
#pragma unroll
        for (int ks = 0; ks < 4; ++ks)
#pragma unroll
            for (int tt = 0; tt < 4; ++tt)
                Bfr[ks][tt] = *(const bf16x8*)(RA + swz<128>(tt * 16 + l15, ks * 32 + q * 8));
        __syncthreads();  // all waves done reading n1; RA writable
#pragma unroll
        for (int part = 0; part < 3; ++part) {
            const int mt = part * 8 + w;
            f32x4 acc[4];
#pragma unroll
            for (int tt = 0; tt < 4; ++tt) acc[tt] = fzero;
#pragma unroll
            for (int ks = 0; ks < 4; ++ks) {
                bf16x8 afr = *(const bf16x8*)(wp + OFF_QKV + ((mt * 4 + ks) * 64 + lane) * 8);
#pragma unroll
                for (int tt = 0; tt < 4; ++tt) acc[tt] = MFMA16(afr, Bfr[ks][tt], acc[tt]);
            }
            const f32x4 bias = *(const f32x4*)(b_qkv + mt * 16 + q * 4);
            if (part == 0) {
#pragma unroll
                for (int tt = 0; tt < 4; ++tt)
                    st4(RA + swz<128>(tt * 16 + l15, w * 16 + q * 4), acc[tt] + bias);
            } else if (part == 1) {
#pragma unroll
                for (int tt = 0; tt < 4; ++tt)
                    st4(RB + swz<128>(tt * 16 + l15, w * 16 + q * 4), acc[tt] + bias);
            } else {
#pragma unroll
                for (int tt = 0; tt < 4; ++tt)
#pragma unroll
                    for (int r = 0; r < 4; ++r)
                        RC[w * 1024 + swz<64>(q * 4 + r, tt * 16 + l15)] =
                            (bf16)(acc[tt][r] + bias[r]);
            }
        }
    }
    // NO BARRIER: stage-4 wave w reads ONLY wave-w-written LDS (Q panel in
    // RA cols 16w.., K panel in RB cols 16w.., V slab RC+w*1024).  Same-wave
    // LDS ops complete in program order -> no sync required.

    // -------- stage 4: attention (wave w = head w), S^T = K.Q^T -------------
    {
        const int colA = w * 16 + (q & 1) * 8;  // HD=16: quads>=2 zero-padded
        const bool hi = (q >= 2);
        const bf16x8 z8 = zero8();
        bf16* const slab = RC + w * 1024;  // [16][64] swz<64>: V^T, then P
        bf16x8 Kf[4];
#pragma unroll
        for (int kt = 0; kt < 4; ++kt) {
            bf16x8 t = *(const bf16x8*)(RB + swz<128>(kt * 16 + l15, colA));
            Kf[kt] = hi ? z8 : t;
        }
        // V frags are qt-independent: load once, then the slab is free for P.
        bf16x8 Vf[2];
#pragma unroll
        for (int ks = 0; ks < 2; ++ks)
            Vf[ks] = *(const bf16x8*)(slab + swz<64>(l15, ks * 32 + q * 8));
#pragma unroll
        for (int qt = 0; qt < 4; ++qt) {
            bf16x8 t = *(const bf16x8*)(RA + swz<128>(qt * 16 + l15, colA));
            bf16x8 Qf = hi ? z8 : t;
            // MAX-FREE softmax over ktok for fixed qtok = qt*16+l15:
            // e^s normalizes identically to e^(s-mx); |s*0.25*log2e|<=~14
            // << 88, no overflow.  exp of S[kt] issues as soon as its MFMA
            // lands.  fp32 normalize BEFORE bf16 quantization.
            float P[4][4];
            float lsum = 0.f;
#pragma unroll
            for (int kt = 0; kt < 4; ++kt) {
                f32x4 S = MFMA16(Kf[kt], Qf, fzero);
#pragma unroll
                for (int r = 0; r < 4; ++r) {
                    const float sv = S[r] * 0.25f;  // HD^-0.5
                    const float e = __builtin_amdgcn_exp2f(sv * 1.4426950408889634f);
                    P[kt][r] = e;
                    lsum += e;
                }
            }
            lsum += __shfl_xor(lsum, 16);
            lsum += __shfl_xor(lsum, 32);
            const float inv = __builtin_amdgcn_rcpf(lsum);
            // normalized P -> slab as [qtok][ktok] bf16
#pragma unroll
            for (int kt = 0; kt < 4; ++kt) {
                f32x4 e4;
#pragma unroll
                for (int r = 0; r < 4; ++r) e4[r] = P[kt][r] * inv;
                st4(slab + swz<64>(l15, kt * 16 + q * 4), e4);
            }
            // O^T = V^T . P^T ; B-frag of P^T == row-contig bf16x8 of P slab
            f32x4 O = fzero;
#pragma unroll
            for (int ks = 0; ks < 2; ++ks) {
                bf16x8 Bf = *(const bf16x8*)(slab + swz<64>(l15, ks * 32 + q * 8));
                O = MFMA16(Vf[ks], Bf, O);
            }
            st4(RA + swz<128>(qt * 16 + l15, w * 16 + q * 4), O);  // over Q rows qt
        }
    }
    __syncthreads();

    // -------- stage 5: x2 += (O . w_proj)^T + b_proj; x2_bf16 -> RB ---------
    {
        f32x4 acc[4];
#pragma unroll
        for (int tt = 0; tt < 4; ++tt) acc[tt] = fzero;
#pragma unroll
        for (int ks = 0; ks < 4; ++ks) {
            bf16x8 afr = *(const bf16x8*)(wp + OFF_PROJ + ((w * 4 + ks) * 64 + lane) * 8);
#pragma unroll
            for (int tt = 0; tt < 4; ++tt) {
                bf16x8 bfr = *(const bf16x8*)(RA + swz<128>(tt * 16 + l15, ks * 32 + q * 8));
                acc[tt] = MFMA16(afr, bfr, acc[tt]);
            }
        }
        const f32x4 bias = *(const f32x4*)(b_proj + w * 16 + q * 4);
#pragma unroll
        for (int tt = 0; tt < 4; ++tt) {
#pragma unroll
            for (int r = 0; r < 4; ++r) x2[tt][r] += acc[tt][r] + bias[r];
            st4(RB + swz<128>(tt * 16 + l15, w * 16 + q * 4), x2[tt]);
        }
    }
    __syncthreads();

    // -------- stage 6: n2 = LN(x2)*g2+b2 : RB -> RA -------------------------
    ln_rows(RB, RA, g2, b2, tid);
    __syncthreads();

    // -------- stage 7: hidden = gelu(w_m1^T . n2^T + b_m1) ------------------
    // n2 consumed into regs; hidden (64x256) split: cols 0:128 -> RB,
    // cols 128:256 -> RC. Writes don't touch RA, so no mid-stage barrier.
    {
        bf16x8 Bfr[4][4];
#pragma unroll
        for (int ks = 0; ks < 4; ++ks)
#pragma unroll
            for (int tt = 0; tt < 4; ++tt)
                Bfr[ks][tt] = *(const bf16x8*)(RA + swz<128>(tt * 16 + l15, ks * 32 + q * 8));
#pragma unroll
        for (int half = 0; half < 2; ++half) {
            const int mt = w * 2 + half;  // 0..15; mt<8 -> RB, else RC
            f32x4 acc[4];
#pragma unroll
            for (int tt = 0; tt < 4; ++tt) acc[tt] = fzero;
#pragma unroll
            for (int ks = 0; ks < 4; ++ks) {
                bf16x8 afr = *(const bf16x8*)(wp + OFF_M1 + ((mt * 4 + ks) * 64 + lane) * 8);
#pragma unroll
                for (int tt = 0; tt < 4; ++tt) acc[tt] = MFMA16(afr, Bfr[ks][tt], acc[tt]);
            }
            const f32x4 bias = *(const f32x4*)(b_m1 + mt * 16 + q * 4);
            bf16* const dst = (mt < 8) ? RB : RC;
            const int colb  = (mt & 7) * 16 + q * 4;
#pragma unroll
            for (int tt = 0; tt < 4; ++tt) {
                f32x4 gl;
#pragma unroll
                for (int r = 0; r < 4; ++r) gl[r] = gelu_f(acc[tt][r] + bias[r]);
                st4(dst + swz<128>(tt * 16 + l15, colb), gl);
            }
        }
    }
    __syncthreads();

    // -------- stage 8: x2 += (hidden . w_m2)^T + b_m2; x2_bf16 -> RA --------
    {
        f32x4 acc[4];
#pragma unroll
        for (int tt = 0; tt < 4; ++tt) acc[tt] = fzero;
#pragma unroll
        for (int ks = 0; ks < 8; ++ks) {
            bf16x8 afr = *(const bf16x8*)(wp + OFF_M2 + ((w * 8 + ks) * 64 + lane) * 8);
            const bf16* const srcH = (ks < 4) ? RB : RC;
            const int colb = (ks & 3) * 32 + q * 8;
#pragma unroll
            for (int tt = 0; tt < 4; ++tt) {
                bf16x8 bfr = *(const bf16x8*)(srcH + swz<128>(tt * 16 + l15, colb));
                acc[tt] = MFMA16(afr, bfr, acc[tt]);
            }
        }
        const f32x4 bias = *(const f32x4*)(b_m2 + w * 16 + q * 4);
#pragma unroll
        for (int tt = 0; tt < 4; ++tt) {
#pragma unroll
            for (int r = 0; r < 4; ++r) x2[tt][r] += acc[tt][r] + bias[r];
            st4(RA + swz<128>(tt * 16 + l15, w * 16 + q * 4), x2[tt]);
        }
    }
    __syncthreads();

    // -------- stage 9: out^T = w_post^T . x2^T + b_post (fp32, dwordx4) -----
    // r4 mapping (proven): wave w owns ct = w>>1, token tiles (w&1)*2+{0,1}.
    {
        const int ct  = w >> 1;        // out-channel tile 0..3
        const int tt0 = (w & 1) * 2;   // token tiles tt0, tt0+1
        f32x4 acc[2];
#pragma unroll
        for (int rr = 0; rr < 2; ++rr) acc[rr] = fzero;
#pragma unroll
        for (int ks = 0; ks < 4; ++ks) {
            bf16x8 afr = *(const bf16x8*)(wp + OFF_POST + ((ct * 4 + ks) * 64 + lane) * 8);
#pragma unroll
            for (int rr = 0; rr < 2; ++rr) {
                bf16x8 bfr = *(const bf16x8*)(RA + swz<128>((tt0 + rr) * 16 + l15, ks * 32 + q * 8));
                acc[rr] = MFMA16(afr, bfr, acc[rr]);
            }
        }
        const f32x4 bias = *(const f32x4*)(b_post + ct * 16 + q * 4);
#pragma unroll
        for (int rr = 0; rr < 2; ++rr) {
            f32x4 v = acc[rr] + bias;
            *(f32x4*)(out + (base + (tt0 + rr) * 16 + l15) * 64 + ct * 16 + q * 4) = v;
        }
    }
}

extern "C" void kernel_launch(void* const* d_in, const int* in_sizes, int n_in,
                              void* d_out, int out_size, void* d_ws, size_t ws_size,
                              hipStream_t stream) {
    const float* feats  = (const float*)d_in[0];
    const float* w_pre  = (const float*)d_in[1];
    const float* b_pre  = (const float*)d_in[2];
    const float* g1     = (const float*)d_in[3];
    const float* b1     = (const float*)d_in[4];
    const float* w_qkv  = (const float*)d_in[5];
    const float* b_qkv  = (const float*)d_in[6];
    const float* w_proj = (const float*)d_in[7];
    const float* b_proj = (const float*)d_in[8];
    const float* g2     = (const float*)d_in[9];
    const float* b2     = (const float*)d_in[10];
    const float* w_m1   = (const float*)d_in[11];
    const float* b_m1   = (const float*)d_in[12];
    const float* w_m2   = (const float*)d_in[13];
    const float* b_m2   = (const float*)d_in[14];
    const float* w_post = (const float*)d_in[15];
    const float* b_post = (const float*)d_in[16];

    bf16* wp = (bf16*)d_ws;  // 288 KB of packed bf16 W^T A-fragments

    pack_all<<<288, 64, 0, stream>>>(w_pre, w_qkv, w_proj, w_m1, w_m2, w_post, wp);

    fused_block_kernel<<<8192, 512, 0, stream>>>(
        feats, wp, b_pre, g1, b1, b_qkv, b_proj, g2, b2, b_m1, b_m2, b_post,
        (float*)d_out);
}

// Round 9
// 621.805 us; speedup vs baseline: 1.3228x; 1.0784x over previous
//
#include <hip/hip_runtime.h>
#include <hip/hip_bf16.h>
#include <math.h>

// ---------------------------------------------------------------------------
// Fully fused transformer block, TRANSPOSED-GEMM formulation.
// One workgroup (512 thr = 8 waves) per 64-token window; 8192 windows.
// Round 9 = round 8 resubmitted verbatim (r8 hit GPUAcquisitionTimeout —
// infra failure, no data; single-variable discipline requires rerunning).
// Round 8 = round 4 (497us, best verified) + max-free softmax ONLY.
//  Evidence history:
//   r3/r5: launch_bounds(512,6) occupancy push -> allocator spill (VGPR 40,
//          +0.5..4.3GB scratch HBM traffic) -> 677..1185us. Lever abandoned.
//   r6: feats-direct global reads -> +180MB FETCH, front-of-block latency
//       -> 673us. Reverted.
//   r7: stage3->4 barrier removal -> wave drift evicts L2-resident weights
//       (FETCH 150->312MB, WRITE 519->606MB) -> 529us. Barrier restored.
//   max-free softmax passed r6 AND r7 (absmax 0.078) with no memory-side
//   mechanism; isolated here on the good base.
//  Max-free softmax: e^s / sum(e^s) == e^(s-mx) / sum(e^(s-mx)); the QK^T
//  logits are bounded (|s*0.25*log2e| <= ~14 << 88) so no overflow. Removes
//  16 fmax + 16 sub + 2 cross-lane shuffles per qt AND breaks the serial
//  "max over all 4 MFMAs before any exp" dependency -> exp2 of S[kt] issues
//  as soon as that MFMA completes.
// Layouts (guide §3, HW-verified): A[m=lane&15][k=quad*8+j],
// B[k=quad*8+j][n=lane&15], D[row=quad*4+reg][col=lane&15].
// ---------------------------------------------------------------------------

typedef __bf16 bf16;
typedef __bf16 bf16x8 __attribute__((ext_vector_type(8)));
typedef __bf16 bf16x4 __attribute__((ext_vector_type(4)));
typedef float  f32x4  __attribute__((ext_vector_type(4)));

#define MFMA16(a, b, c) __builtin_amdgcn_mfma_f32_16x16x32_bf16((a), (b), (c), 0, 0, 0)

// packed-weight element offsets inside d_ws (bf16 elements)
constexpr int OFF_PRE  = 0;       // w_pre  64x128 : KT=2, MT=8  -> 16 tiles
constexpr int OFF_QKV  = 8192;    // w_qkv 128x384 : KT=4, MT=24 -> 96 tiles
constexpr int OFF_PROJ = 57344;   // w_proj128x128 : KT=4, MT=8  -> 32 tiles
constexpr int OFF_M1   = 73728;   // w_m1  128x256 : KT=4, MT=16 -> 64 tiles
constexpr int OFF_M2   = 106496;  // w_m2  256x128 : KT=8, MT=8  -> 64 tiles
constexpr int OFF_POST = 139264;  // w_post128x64  : KT=4, MT=4  -> 16 tiles
// total 147456 bf16 = 288 KB in d_ws

// XOR-swizzled row-major layout (16B chunks XOR row) -> conflict-light
// ds_read_b128 / ds_write_b64 without padding.
template <int W>
__device__ __forceinline__ int swz(int row, int col) {
    constexpr int CH = W >> 3;
    constexpr int M  = (CH - 1) < 15 ? (CH - 1) : 15;
    const int c = (col >> 3) ^ (row & M);
    return row * W + c * 8 + (col & 7);
}

__device__ __forceinline__ bf16x8 zero8() {
    bf16x8 z;
#pragma unroll
    for (int j = 0; j < 8; ++j) z[j] = (bf16)0.0f;
    return z;
}

// store 4 fp32 as 4 consecutive bf16 (8B). col base is 4-aligned -> stays
// inside one 8-elem swizzle chunk -> single ds_write_b64.
__device__ __forceinline__ void st4(bf16* p, const f32x4 v) {
    bf16x4 o;
#pragma unroll
    for (int r = 0; r < 4; ++r) o[r] = (bf16)v[r];
    *(bf16x4*)p = o;
}

// fast gelu: x * sigmoid(2u), u = 0.79788456(x + 0.044715 x^3)
__device__ __forceinline__ float gelu_f(float x) {
    const float u = 0.79788456f * x * (1.0f + 0.044715f * x * x);
    const float e = __builtin_amdgcn_exp2f(u * 2.8853900817779268f);  // e^(2u)
    return x - x * __builtin_amdgcn_rcpf(e + 1.0f);  // robust at e->inf
}

// ---------------------------------------------------------------------------
// Weight packer: fp32 W[K][N] -> A-frag tiles of W^T (== B-frag tiles of W).
// Tile (mt,kt): lane l, frag[j] = W[kt*32 + (l>>4)*8 + j][mt*16 + (l&15)].
// All six weights in ONE kernel (288 blocks) to avoid 6 launch latencies.
// ---------------------------------------------------------------------------
__global__ void pack_all(const float* __restrict__ w_pre,
                         const float* __restrict__ w_qkv,
                         const float* __restrict__ w_proj,
                         const float* __restrict__ w_m1,
                         const float* __restrict__ w_m2,
                         const float* __restrict__ w_post,
                         bf16* __restrict__ dst) {
    const int t = blockIdx.x;
    const float* src;
    int Ncol, KT, off, t0;
    if (t < 16)       { src = w_pre;  Ncol = 128; KT = 2; off = OFF_PRE;  t0 = 0; }
    else if (t < 112) { src = w_qkv;  Ncol = 384; KT = 4; off = OFF_QKV;  t0 = 16; }
    else if (t < 144) { src = w_proj; Ncol = 128; KT = 4; off = OFF_PROJ; t0 = 112; }
    else if (t < 208) { src = w_m1;   Ncol = 256; KT = 4; off = OFF_M1;   t0 = 144; }
    else if (t < 272) { src = w_m2;   Ncol = 128; KT = 8; off = OFF_M2;   t0 = 208; }
    else              { src = w_post; Ncol = 64;  KT = 4; off = OFF_POST; t0 = 272; }
    const int tile = t - t0;
    const int lane = threadIdx.x;
    const int mt = tile / KT, kt = tile - mt * KT;
    const int n  = mt * 16 + (lane & 15);
    const int k0 = kt * 32 + (lane >> 4) * 8;
    bf16x8 v;
#pragma unroll
    for (int j = 0; j < 8; ++j) v[j] = (bf16)src[(k0 + j) * Ncol + n];
    // NOTE: destination MUST include the per-weight region offset `off`.
    *(bf16x8*)(dst + off + ((long)(tile * 64 + lane)) * 8) = v;
}

// LayerNorm over 128 channels: 8 lanes per row, shuffle-reduce, bf16 out.
__device__ __forceinline__ void ln_rows(const bf16* __restrict__ in,
                                        bf16* __restrict__ outb,
                                        const float* __restrict__ g,
                                        const float* __restrict__ b, int tid) {
    const int row = tid >> 3, sub = tid & 7;
    bf16x8 c0 = *(const bf16x8*)(in + swz<128>(row, sub * 16));
    bf16x8 c1 = *(const bf16x8*)(in + swz<128>(row, sub * 16 + 8));
    float v[16];
#pragma unroll
    for (int j = 0; j < 8; ++j) { v[j] = (float)c0[j]; v[8 + j] = (float)c1[j]; }
    float s = 0.f, ss = 0.f;
#pragma unroll
    for (int j = 0; j < 16; ++j) { s += v[j]; ss += v[j] * v[j]; }
#pragma unroll
    for (int m = 1; m <= 4; m <<= 1) {
        s += __shfl_xor(s, m);
        ss += __shfl_xor(ss, m);
    }
    const float mu   = s * (1.0f / 128.0f);
    const float rstd = __builtin_amdgcn_rsqf(ss * (1.0f / 128.0f) - mu * mu + 1e-5f);
    bf16x8 o0, o1;
#pragma unroll
    for (int j = 0; j < 8; ++j) {
        o0[j] = (bf16)((v[j] - mu) * rstd * g[sub * 16 + j] + b[sub * 16 + j]);
        o1[j] = (bf16)((v[8 + j] - mu) * rstd * g[sub * 16 + 8 + j] + b[sub * 16 + 8 + j]);
    }
    *(bf16x8*)(outb + swz<128>(row, sub * 16)) = o0;
    *(bf16x8*)(outb + swz<128>(row, sub * 16 + 8)) = o1;
}

__global__ __launch_bounds__(512, 4)
void fused_block_kernel(const float* __restrict__ feats,
                        const bf16* __restrict__ wp,
                        const float* __restrict__ b_pre,
                        const float* __restrict__ g1, const float* __restrict__ b1,
                        const float* __restrict__ b_qkv,
                        const float* __restrict__ b_proj,
                        const float* __restrict__ g2, const float* __restrict__ b2,
                        const float* __restrict__ b_m1,
                        const float* __restrict__ b_m2,
                        const float* __restrict__ b_post,
                        float* __restrict__ out) {
    // 48 KB static LDS, three 16 KB regions, time-multiplexed:
    //  RA: feats(8KB, swz<64>) -> n1 -> Q -> O -> n2 -> x2_bf16(post input)
    //  RB: x2_bf16(LN1 in) -> K -> x2_bf16(LN2 in) -> hidden[:,0:128]
    //  RC: per-wave slabs (V^T then P, 1024 elems each) -> hidden[:,128:256]
    // Lifetime rules: a region is overwritten only after (a) an all-wave
    // barrier past its last cross-wave read, or (b) it is same-wave-private.
    __shared__ __align__(16) bf16 RA[64 * 128];
    __shared__ __align__(16) bf16 RB[64 * 128];
    __shared__ __align__(16) bf16 RC[64 * 128];

    const int tid  = threadIdx.x;
    const int w    = tid >> 6;   // wave 0..7 == head / out-channel-tile owner
    const int lane = tid & 63;
    const int q    = lane >> 4;  // quad
    const int l15  = lane & 15;
    const long base = (long)blockIdx.x * 64;
    const f32x4 fzero = {0.f, 0.f, 0.f, 0.f};

    // -------- stage 0: feats (64x64 fp32) -> RA bf16, swizzled --------------
    {
        const int row = tid >> 3, ch = tid & 7;
        const float* src = feats + (base + row) * 64 + ch * 8;
        float4 a = *(const float4*)src;
        float4 b = *(const float4*)(src + 4);
        bf16x8 v;
        v[0] = (bf16)a.x; v[1] = (bf16)a.y; v[2] = (bf16)a.z; v[3] = (bf16)a.w;
        v[4] = (bf16)b.x; v[5] = (bf16)b.y; v[6] = (bf16)b.z; v[7] = (bf16)b.w;
        *(bf16x8*)(RA + swz<64>(row, ch * 8)) = v;
    }
    __syncthreads();

    // residual stream in regs: x2[tt][r] = x2[token tt*16+l15][ch w*16+q*4+r]
    f32x4 x2[4];

    // -------- stage 1: x2^T = w_pre^T . feats^T + b_pre; x2_bf16 -> RB ------
    {
        f32x4 acc[4];
#pragma unroll
        for (int tt = 0; tt < 4; ++tt) acc[tt] = fzero;
#pragma unroll
        for (int ks = 0; ks < 2; ++ks) {
            bf16x8 afr = *(const bf16x8*)(wp + OFF_PRE + ((w * 2 + ks) * 64 + lane) * 8);
#pragma unroll
            for (int tt = 0; tt < 4; ++tt) {
                bf16x8 bfr = *(const bf16x8*)(RA + swz<64>(tt * 16 + l15, ks * 32 + q * 8));
                acc[tt] = MFMA16(afr, bfr, acc[tt]);
            }
        }
        const f32x4 bias = *(const f32x4*)(b_pre + w * 16 + q * 4);
#pragma unroll
        for (int tt = 0; tt < 4; ++tt) {
#pragma unroll
            for (int r = 0; r < 4; ++r) x2[tt][r] = acc[tt][r] + bias[r];
            st4(RB + swz<128>(tt * 16 + l15, w * 16 + q * 4), x2[tt]);
        }
    }
    __syncthreads();

    // -------- stage 2: n1 = LN(x2)*g1+b1 : RB -> RA -------------------------
    ln_rows(RB, RA, g1, b1, tid);
    __syncthreads();

    // -------- stage 3: qkv^T = w_qkv^T . n1^T + b_qkv -----------------------
    // n1 consumed into regs first, then RA is reused for Q (barrier between).
    // wave w: Q head w -> RA (cols 16w..), K head w -> RB (cols 16w..),
    // V head w -> RC slab w, transposed [ch][tok].
    {
        bf16x8 Bfr[4][4];
#pragma unroll
        for (int ks = 0; ks < 4; ++ks)
#pragma unroll
            for (int tt = 0; tt < 4; ++tt)
                Bfr[ks][tt] = *(const bf16x8*)(RA + swz<128>(tt * 16 + l15, ks * 32 + q * 8));
        __syncthreads();  // all waves done reading n1; RA writable
#pragma unroll
        for (int part = 0; part < 3; ++part) {
            const int mt = part * 8 + w;
            f32x4 acc[4];
#pragma unroll
            for (int tt = 0; tt < 4; ++tt) acc[tt] = fzero;
#pragma unroll
            for (int ks = 0; ks < 4; ++ks) {
                bf16x8 afr = *(const bf16x8*)(wp + OFF_QKV + ((mt * 4 + ks) * 64 + lane) * 8);
#pragma unroll
                for (int tt = 0; tt < 4; ++tt) acc[tt] = MFMA16(afr, Bfr[ks][tt], acc[tt]);
            }
            const f32x4 bias = *(const f32x4*)(b_qkv + mt * 16 + q * 4);
            if (part == 0) {
#pragma unroll
                for (int tt = 0; tt < 4; ++tt)
                    st4(RA + swz<128>(tt * 16 + l15, w * 16 + q * 4), acc[tt] + bias);
            } else if (part == 1) {
#pragma unroll
                for (int tt = 0; tt < 4; ++tt)
                    st4(RB + swz<128>(tt * 16 + l15, w * 16 + q * 4), acc[tt] + bias);
            } else {
#pragma unroll
                for (int tt = 0; tt < 4; ++tt)
#pragma unroll
                    for (int r = 0; r < 4; ++r)
                        RC[w * 1024 + swz<64>(q * 4 + r, tt * 16 + l15)] =
                            (bf16)(acc[tt][r] + bias[r]);
            }
        }
    }
    __syncthreads();  // KEEP: removing it (r7) caused wave drift -> L2 weight
                      // eviction (FETCH +163MB) -> +32us. Lockstep is faster.

    // -------- stage 4: attention (wave w = head w), S^T = K.Q^T -------------
    {
        const int colA = w * 16 + (q & 1) * 8;  // HD=16: quads>=2 zero-padded
        const bool hi = (q >= 2);
        const bf16x8 z8 = zero8();
        bf16* const slab = RC + w * 1024;  // [16][64] swz<64>: V^T, then P
        bf16x8 Kf[4];
#pragma unroll
        for (int kt = 0; kt < 4; ++kt) {
            bf16x8 t = *(const bf16x8*)(RB + swz<128>(kt * 16 + l15, colA));
            Kf[kt] = hi ? z8 : t;
        }
        // V frags are qt-independent: load once, then the slab is free for P.
        bf16x8 Vf[2];
#pragma unroll
        for (int ks = 0; ks < 2; ++ks)
            Vf[ks] = *(const bf16x8*)(slab + swz<64>(l15, ks * 32 + q * 8));
#pragma unroll
        for (int qt = 0; qt < 4; ++qt) {
            bf16x8 t = *(const bf16x8*)(RA + swz<128>(qt * 16 + l15, colA));
            bf16x8 Qf = hi ? z8 : t;
            // MAX-FREE softmax over ktok for fixed qtok = qt*16+l15:
            // e^s normalizes identically to e^(s-mx); |s*0.25*log2e|<=~14
            // << 88, no overflow.  exp of S[kt] issues as soon as its MFMA
            // lands.  fp32 normalize BEFORE bf16 quantization.
            float P[4][4];
            float lsum = 0.f;
#pragma unroll
            for (int kt = 0; kt < 4; ++kt) {
                f32x4 S = MFMA16(Kf[kt], Qf, fzero);
#pragma unroll
                for (int r = 0; r < 4; ++r) {
                    const float sv = S[r] * 0.25f;  // HD^-0.5
                    const float e = __builtin_amdgcn_exp2f(sv * 1.4426950408889634f);
                    P[kt][r] = e;
                    lsum += e;
                }
            }
            lsum += __shfl_xor(lsum, 16);
            lsum += __shfl_xor(lsum, 32);
            const float inv = __builtin_amdgcn_rcpf(lsum);
            // normalized P -> slab as [qtok][ktok] bf16
#pragma unroll
            for (int kt = 0; kt < 4; ++kt) {
                f32x4 e4;
#pragma unroll
                for (int r = 0; r < 4; ++r) e4[r] = P[kt][r] * inv;
                st4(slab + swz<64>(l15, kt * 16 + q * 4), e4);
            }
            // O^T = V^T . P^T ; B-frag of P^T == row-contig bf16x8 of P slab
            f32x4 O = fzero;
#pragma unroll
            for (int ks = 0; ks < 2; ++ks) {
                bf16x8 Bf = *(const bf16x8*)(slab + swz<64>(l15, ks * 32 + q * 8));
                O = MFMA16(Vf[ks], Bf, O);
            }
            st4(RA + swz<128>(qt * 16 + l15, w * 16 + q * 4), O);  // over Q rows qt
        }
    }
    __syncthreads();

    // -------- stage 5: x2 += (O . w_proj)^T + b_proj; x2_bf16 -> RB ---------
    {
        f32x4 acc[4];
#pragma unroll
        for (int tt = 0; tt < 4; ++tt) acc[tt] = fzero;
#pragma unroll
        for (int ks = 0; ks < 4; ++ks) {
            bf16x8 afr = *(const bf16x8*)(wp + OFF_PROJ + ((w * 4 + ks) * 64 + lane) * 8);
#pragma unroll
            for (int tt = 0; tt < 4; ++tt) {
                bf16x8 bfr = *(const bf16x8*)(RA + swz<128>(tt * 16 + l15, ks * 32 + q * 8));
                acc[tt] = MFMA16(afr, bfr, acc[tt]);
            }
        }
        const f32x4 bias = *(const f32x4*)(b_proj + w * 16 + q * 4);
#pragma unroll
        for (int tt = 0; tt < 4; ++tt) {
#pragma unroll
            for (int r = 0; r < 4; ++r) x2[tt][r] += acc[tt][r] + bias[r];
            st4(RB + swz<128>(tt * 16 + l15, w * 16 + q * 4), x2[tt]);
        }
    }
    __syncthreads();

    // -------- stage 6: n2 = LN(x2)*g2+b2 : RB -> RA -------------------------
    ln_rows(RB, RA, g2, b2, tid);
    __syncthreads();

    // -------- stage 7: hidden = gelu(w_m1^T . n2^T + b_m1) ------------------
    // n2 consumed into regs; hidden (64x256) split: cols 0:128 -> RB,
    // cols 128:256 -> RC. Writes don't touch RA, so no mid-stage barrier.
    {
        bf16x8 Bfr[4][4];
#pragma unroll
        for (int ks = 0; ks < 4; ++ks)
#pragma unroll
            for (int tt = 0; tt < 4; ++tt)
                Bfr[ks][tt] = *(const bf16x8*)(RA + swz<128>(tt * 16 + l15, ks * 32 + q * 8));
#pragma unroll
        for (int half = 0; half < 2; ++half) {
            const int mt = w * 2 + half;  // 0..15; mt<8 -> RB, else RC
            f32x4 acc[4];
#pragma unroll
            for (int tt = 0; tt < 4; ++tt) acc[tt] = fzero;
#pragma unroll
            for (int ks = 0; ks < 4; ++ks) {
                bf16x8 afr = *(const bf16x8*)(wp + OFF_M1 + ((mt * 4 + ks) * 64 + lane) * 8);
#pragma unroll
                for (int tt = 0; tt < 4; ++tt) acc[tt] = MFMA16(afr, Bfr[ks][tt], acc[tt]);
            }
            const f32x4 bias = *(const f32x4*)(b_m1 + mt * 16 + q * 4);
            bf16* const dst = (mt < 8) ? RB : RC;
            const int colb  = (mt & 7) * 16 + q * 4;
#pragma unroll
            for (int tt = 0; tt < 4; ++tt) {
                f32x4 gl;
#pragma unroll
                for (int r = 0; r < 4; ++r) gl[r] = gelu_f(acc[tt][r] + bias[r]);
                st4(dst + swz<128>(tt * 16 + l15, colb), gl);
            }
        }
    }
    __syncthreads();

    // -------- stage 8: x2 += (hidden . w_m2)^T + b_m2; x2_bf16 -> RA --------
    {
        f32x4 acc[4];
#pragma unroll
        for (int tt = 0; tt < 4; ++tt) acc[tt] = fzero;
#pragma unroll
        for (int ks = 0; ks < 8; ++ks) {
            bf16x8 afr = *(const bf16x8*)(wp + OFF_M2 + ((w * 8 + ks) * 64 + lane) * 8);
            const bf16* const srcH = (ks < 4) ? RB : RC;
            const int colb = (ks & 3) * 32 + q * 8;
#pragma unroll
            for (int tt = 0; tt < 4; ++tt) {
                bf16x8 bfr = *(const bf16x8*)(srcH + swz<128>(tt * 16 + l15, colb));
                acc[tt] = MFMA16(afr, bfr, acc[tt]);
            }
        }
        const f32x4 bias = *(const f32x4*)(b_m2 + w * 16 + q * 4);
#pragma unroll
        for (int tt = 0; tt < 4; ++tt) {
#pragma unroll
            for (int r = 0; r < 4; ++r) x2[tt][r] += acc[tt][r] + bias[r];
            st4(RA + swz<128>(tt * 16 + l15, w * 16 + q * 4), x2[tt]);
        }
    }
    __syncthreads();

    // -------- stage 9: out^T = w_post^T . x2^T + b_post (fp32, dwordx4) -----
    // r4 mapping (proven): wave w owns ct = w>>1, token tiles (w&1)*2+{0,1}.
    {
        const int ct  = w >> 1;        // out-channel tile 0..3
        const int tt0 = (w & 1) * 2;   // token tiles tt0, tt0+1
        f32x4 acc[2];
#pragma unroll
        for (int rr = 0; rr < 2; ++rr) acc[rr] = fzero;
#pragma unroll
        for (int ks = 0; ks < 4; ++ks) {
            bf16x8 afr = *(const bf16x8*)(wp + OFF_POST + ((ct * 4 + ks) * 64 + lane) * 8);
#pragma unroll
            for (int rr = 0; rr < 2; ++rr) {
                bf16x8 bfr = *(const bf16x8*)(RA + swz<128>((tt0 + rr) * 16 + l15, ks * 32 + q * 8));
                acc[rr] = MFMA16(afr, bfr, acc[rr]);
            }
        }
        const f32x4 bias = *(const f32x4*)(b_post + ct * 16 + q * 4);
#pragma unroll
        for (int rr = 0; rr < 2; ++rr) {
            f32x4 v = acc[rr] + bias;
            *(f32x4*)(out + (base + (tt0 + rr) * 16 + l15) * 64 + ct * 16 + q * 4) = v;
        }
    }
}

extern "C" void kernel_launch(void* const* d_in, const int* in_sizes, int n_in,
                              void* d_out, int out_size, void* d_ws, size_t ws_size,
                              hipStream_t stream) {
    const float* feats  = (const float*)d_in[0];
    const float* w_pre  = (const float*)d_in[1];
    const float* b_pre  = (const float*)d_in[2];
    const float* g1     = (const float*)d_in[3];
    const float* b1     = (const float*)d_in[4];
    const float* w_qkv  = (const float*)d_in[5];
    const float* b_qkv  = (const float*)d_in[6];
    const float* w_proj = (const float*)d_in[7];
    const float* b_proj = (const float*)d_in[8];
    const float* g2     = (const float*)d_in[9];
    const float* b2     = (const float*)d_in[10];
    const float* w_m1   = (const float*)d_in[11];
    const float* b_m1   = (const float*)d_in[12];
    const float* w_m2   = (const float*)d_in[13];
    const float* b_m2   = (const float*)d_in[14];
    const float* w_post = (const float*)d_in[15];
    const float* b_post = (const float*)d_in[16];

    bf16* wp = (bf16*)d_ws;  // 288 KB of packed bf16 W^T A-fragments

    pack_all<<<288, 64, 0, stream>>>(w_pre, w_qkv, w_proj, w_m1, w_m2, w_post, wp);

    fused_block_kernel<<<8192, 512, 0, stream>>>(
        feats, wp, b_pre, g1, b1, b_qkv, b_proj, g2, b2, b_m1, b_m2, b_post,
        (float*)d_out);
}

// Round 13
// 618.898 us; speedup vs baseline: 1.3290x; 1.0047x over previous
//
#include <hip/hip_runtime.h>
#include <hip/hip_bf16.h>
#include <math.h>

// ---------------------------------------------------------------------------
// Fully fused transformer block, TRANSPOSED-GEMM formulation.
// One workgroup (512 thr = 8 waves) per 64-token window; 8192 windows.
// Round 13 = round 10 kernel, FOURTH submission (r10: container failed twice,
// r11/r12: GPUAcquisitionTimeout — all infra, zero data; single-variable
// discipline requires rerunning unchanged).
// Round 10 (base = round 9, 483us verified, best):
//  * NEW: cross-barrier weight prefetch. hipcc drains vmcnt(0) at every
//    s_barrier and cannot hoist loads across __syncthreads; issuing each
//    stage's weight-fragment loads BEFORE the preceding barrier hides their
//    ~200+cyc L2 latency under work+barrier-wait, guaranteed-complete after.
//    Covered: PRE (stage0), QKV part-0 (stage-3 preload window), PROJ
//    (stage4), M1 (stage5), M2 (stage-7 end), POST (stage8).
//  * stage 7 restructured tt-outer (Bfr[4] = 16 regs, was Bfr[4][4] = 64)
//    to keep peak register pressure at stage 3 despite pfM1/pfM2 (+32 regs
//    each). Per-output-element ks accumulation order unchanged -> bit-
//    identical numerics.
//  * All placements chosen below the stage-3 register peak -> occupancy
//    and spill behavior should be unchanged (FETCH flat = no-spill tripwire).
//  KEPT from r9: max-free softmax; all barriers (r7: removal -> wave drift
//  -> L2 weight eviction, +46us); LDS 48KB 3-region overlay; P^T via LDS
//  round-trip through dead V slab; launch_bounds(512,4) (r3/r5: bounds-6
//  spills).
// Layouts (guide §3, HW-verified): A[m=lane&15][k=quad*8+j],
// B[k=quad*8+j][n=lane&15], D[row=quad*4+reg][col=lane&15].
// ---------------------------------------------------------------------------

typedef __bf16 bf16;
typedef __bf16 bf16x8 __attribute__((ext_vector_type(8)));
typedef __bf16 bf16x4 __attribute__((ext_vector_type(4)));
typedef float  f32x4  __attribute__((ext_vector_type(4)));

#define MFMA16(a, b, c) __builtin_amdgcn_mfma_f32_16x16x32_bf16((a), (b), (c), 0, 0, 0)

// packed-weight element offsets inside d_ws (bf16 elements)
constexpr int OFF_PRE  = 0;       // w_pre  64x128 : KT=2, MT=8  -> 16 tiles
constexpr int OFF_QKV  = 8192;    // w_qkv 128x384 : KT=4, MT=24 -> 96 tiles
constexpr int OFF_PROJ = 57344;   // w_proj128x128 : KT=4, MT=8  -> 32 tiles
constexpr int OFF_M1   = 73728;   // w_m1  128x256 : KT=4, MT=16 -> 64 tiles
constexpr int OFF_M2   = 106496;  // w_m2  256x128 : KT=8, MT=8  -> 64 tiles
constexpr int OFF_POST = 139264;  // w_post128x64  : KT=4, MT=4  -> 16 tiles
// total 147456 bf16 = 288 KB in d_ws

// XOR-swizzled row-major layout (16B chunks XOR row) -> conflict-light
// ds_read_b128 / ds_write_b64 without padding.
template <int W>
__device__ __forceinline__ int swz(int row, int col) {
    constexpr int CH = W >> 3;
    constexpr int M  = (CH - 1) < 15 ? (CH - 1) : 15;
    const int c = (col >> 3) ^ (row & M);
    return row * W + c * 8 + (col & 7);
}

__device__ __forceinline__ bf16x8 zero8() {
    bf16x8 z;
#pragma unroll
    for (int j = 0; j < 8; ++j) z[j] = (bf16)0.0f;
    return z;
}

// store 4 fp32 as 4 consecutive bf16 (8B). col base is 4-aligned -> stays
// inside one 8-elem swizzle chunk -> single ds_write_b64.
__device__ __forceinline__ void st4(bf16* p, const f32x4 v) {
    bf16x4 o;
#pragma unroll
    for (int r = 0; r < 4; ++r) o[r] = (bf16)v[r];
    *(bf16x4*)p = o;
}

// fast gelu: x * sigmoid(2u), u = 0.79788456(x + 0.044715 x^3)
__device__ __forceinline__ float gelu_f(float x) {
    const float u = 0.79788456f * x * (1.0f + 0.044715f * x * x);
    const float e = __builtin_amdgcn_exp2f(u * 2.8853900817779268f);  // e^(2u)
    return x - x * __builtin_amdgcn_rcpf(e + 1.0f);  // robust at e->inf
}

// ---------------------------------------------------------------------------
// Weight packer: fp32 W[K][N] -> A-frag tiles of W^T (== B-frag tiles of W).
// Tile (mt,kt): lane l, frag[j] = W[kt*32 + (l>>4)*8 + j][mt*16 + (l&15)].
// All six weights in ONE kernel (288 blocks) to avoid 6 launch latencies.
// ---------------------------------------------------------------------------
__global__ void pack_all(const float* __restrict__ w_pre,
                         const float* __restrict__ w_qkv,
                         const float* __restrict__ w_proj,
                         const float* __restrict__ w_m1,
                         const float* __restrict__ w_m2,
                         const float* __restrict__ w_post,
                         bf16* __restrict__ dst) {
    const int t = blockIdx.x;
    const float* src;
    int Ncol, KT, off, t0;
    if (t < 16)       { src = w_pre;  Ncol = 128; KT = 2; off = OFF_PRE;  t0 = 0; }
    else if (t < 112) { src = w_qkv;  Ncol = 384; KT = 4; off = OFF_QKV;  t0 = 16; }
    else if (t < 144) { src = w_proj; Ncol = 128; KT = 4; off = OFF_PROJ; t0 = 112; }
    else if (t < 208) { src = w_m1;   Ncol = 256; KT = 4; off = OFF_M1;   t0 = 144; }
    else if (t < 272) { src = w_m2;   Ncol = 128; KT = 8; off = OFF_M2;   t0 = 208; }
    else              { src = w_post; Ncol = 64;  KT = 4; off = OFF_POST; t0 = 272; }
    const int tile = t - t0;
    const int lane = threadIdx.x;
    const int mt = tile / KT, kt = tile - mt * KT;
    const int n  = mt * 16 + (lane & 15);
    const int k0 = kt * 32 + (lane >> 4) * 8;
    bf16x8 v;
#pragma unroll
    for (int j = 0; j < 8; ++j) v[j] = (bf16)src[(k0 + j) * Ncol + n];
    // NOTE: destination MUST include the per-weight region offset `off`.
    *(bf16x8*)(dst + off + ((long)(tile * 64 + lane)) * 8) = v;
}

// LayerNorm over 128 channels: 8 lanes per row, shuffle-reduce, bf16 out.
__device__ __forceinline__ void ln_rows(const bf16* __restrict__ in,
                                        bf16* __restrict__ outb,
                                        const float* __restrict__ g,
                                        const float* __restrict__ b, int tid) {
    const int row = tid >> 3, sub = tid & 7;
    bf16x8 c0 = *(const bf16x8*)(in + swz<128>(row, sub * 16));
    bf16x8 c1 = *(const bf16x8*)(in + swz<128>(row, sub * 16 + 8));
    float v[16];
#pragma unroll
    for (int j = 0; j < 8; ++j) { v[j] = (float)c0[j]; v[8 + j] = (float)c1[j]; }
    float s = 0.f, ss = 0.f;
#pragma unroll
    for (int j = 0; j < 16; ++j) { s += v[j]; ss += v[j] * v[j]; }
#pragma unroll
    for (int m = 1; m <= 4; m <<= 1) {
        s += __shfl_xor(s, m);
        ss += __shfl_xor(ss, m);
    }
    const float mu   = s * (1.0f / 128.0f);
    const float rstd = __builtin_amdgcn_rsqf(ss * (1.0f / 128.0f) - mu * mu + 1e-5f);
    bf16x8 o0, o1;
#pragma unroll
    for (int j = 0; j < 8; ++j) {
        o0[j] = (bf16)((v[j] - mu) * rstd * g[sub * 16 + j] + b[sub * 16 + j]);
        o1[j] = (bf16)((v[8 + j] - mu) * rstd * g[sub * 16 + 8 + j] + b[sub * 16 + 8 + j]);
    }
    *(bf16x8*)(outb + swz<128>(row, sub * 16)) = o0;
    *(bf16x8*)(outb + swz<128>(row, sub * 16 + 8)) = o1;
}

__global__ __launch_bounds__(512, 4)
void fused_block_kernel(const float* __restrict__ feats,
                        const bf16* __restrict__ wp,
                        const float* __restrict__ b_pre,
                        const float* __restrict__ g1, const float* __restrict__ b1,
                        const float* __restrict__ b_qkv,
                        const float* __restrict__ b_proj,
                        const float* __restrict__ g2, const float* __restrict__ b2,
                        const float* __restrict__ b_m1,
                        const float* __restrict__ b_m2,
                        const float* __restrict__ b_post,
                        float* __restrict__ out) {
    // 48 KB static LDS, three 16 KB regions, time-multiplexed:
    //  RA: feats(8KB, swz<64>) -> n1 -> Q -> O -> n2 -> x2_bf16(post input)
    //  RB: x2_bf16(LN1 in) -> K -> x2_bf16(LN2 in) -> hidden[:,0:128]
    //  RC: per-wave slabs (V^T then P, 1024 elems each) -> hidden[:,128:256]
    // Lifetime rules: a region is overwritten only after (a) an all-wave
    // barrier past its last cross-wave read, or (b) it is same-wave-private.
    __shared__ __align__(16) bf16 RA[64 * 128];
    __shared__ __align__(16) bf16 RB[64 * 128];
    __shared__ __align__(16) bf16 RC[64 * 128];

    const int tid  = threadIdx.x;
    const int w    = tid >> 6;   // wave 0..7 == head / out-channel-tile owner
    const int lane = tid & 63;
    const int q    = lane >> 4;  // quad
    const int l15  = lane & 15;
    const long base = (long)blockIdx.x * 64;
    const f32x4 fzero = {0.f, 0.f, 0.f, 0.f};

    // -------- stage 0: feats (64x64 fp32) -> RA bf16, swizzled --------------
    bf16x8 pfPRE[2];
    {
        const int row = tid >> 3, ch = tid & 7;
        const float* src = feats + (base + row) * 64 + ch * 8;
        float4 a = *(const float4*)src;
        float4 b = *(const float4*)(src + 4);
        // prefetch stage-1 weights: in flight during cvt/store, drained at
        // the barrier (compiler emits vmcnt(0) before s_barrier).
#pragma unroll
        for (int ks = 0; ks < 2; ++ks)
            pfPRE[ks] = *(const bf16x8*)(wp + OFF_PRE + ((w * 2 + ks) * 64 + lane) * 8);
        bf16x8 v;
        v[0] = (bf16)a.x; v[1] = (bf16)a.y; v[2] = (bf16)a.z; v[3] = (bf16)a.w;
        v[4] = (bf16)b.x; v[5] = (bf16)b.y; v[6] = (bf16)b.z; v[7] = (bf16)b.w;
        *(bf16x8*)(RA + swz<64>(row, ch * 8)) = v;
    }
    __syncthreads();

    // residual stream in regs: x2[tt][r] = x2[token tt*16+l15][ch w*16+q*4+r]
    f32x4 x2[4];

    // -------- stage 1: x2^T = w_pre^T . feats^T + b_pre; x2_bf16 -> RB ------
    {
        f32x4 acc[4];
#pragma unroll
        for (int tt = 0; tt < 4; ++tt) acc[tt] = fzero;
#pragma unroll
        for (int ks = 0; ks < 2; ++ks) {
#pragma unroll
            for (int tt = 0; tt < 4; ++tt) {
                bf16x8 bfr = *(const bf16x8*)(RA + swz<64>(tt * 16 + l15, ks * 32 + q * 8));
                acc[tt] = MFMA16(pfPRE[ks], bfr, acc[tt]);
            }
        }
        const f32x4 bias = *(const f32x4*)(b_pre + w * 16 + q * 4);
#pragma unroll
        for (int tt = 0; tt < 4; ++tt) {
#pragma unroll
            for (int r = 0; r < 4; ++r) x2[tt][r] = acc[tt][r] + bias[r];
            st4(RB + swz<128>(tt * 16 + l15, w * 16 + q * 4), x2[tt]);
        }
    }
    __syncthreads();

    // -------- stage 2: n1 = LN(x2)*g1+b1 : RB -> RA -------------------------
    ln_rows(RB, RA, g1, b1, tid);
    __syncthreads();

    // -------- stage 3: qkv^T = w_qkv^T . n1^T + b_qkv -----------------------
    // n1 consumed into regs first, then RA is reused for Q (barrier between).
    // wave w: Q head w -> RA (cols 16w..), K head w -> RB (cols 16w..),
    // V head w -> RC slab w, transposed [ch][tok].
    // Part-0 (Q) weights prefetched during the Bfr ds_read preload + barrier.
    {
        bf16x8 pfQ[4];
#pragma unroll
        for (int ks = 0; ks < 4; ++ks)
            pfQ[ks] = *(const bf16x8*)(wp + OFF_QKV + ((w * 4 + ks) * 64 + lane) * 8);
        bf16x8 Bfr[4][4];
#pragma unroll
        for (int ks = 0; ks < 4; ++ks)
#pragma unroll
            for (int tt = 0; tt < 4; ++tt)
                Bfr[ks][tt] = *(const bf16x8*)(RA + swz<128>(tt * 16 + l15, ks * 32 + q * 8));
        __syncthreads();  // all waves done reading n1; RA writable
#pragma unroll
        for (int part = 0; part < 3; ++part) {
            const int mt = part * 8 + w;
            f32x4 acc[4];
#pragma unroll
            for (int tt = 0; tt < 4; ++tt) acc[tt] = fzero;
#pragma unroll
            for (int ks = 0; ks < 4; ++ks) {
                bf16x8 afr = (part == 0)
                    ? pfQ[ks]
                    : *(const bf16x8*)(wp + OFF_QKV + ((mt * 4 + ks) * 64 + lane) * 8);
#pragma unroll
                for (int tt = 0; tt < 4; ++tt) acc[tt] = MFMA16(afr, Bfr[ks][tt], acc[tt]);
            }
            const f32x4 bias = *(const f32x4*)(b_qkv + mt * 16 + q * 4);
            if (part == 0) {
#pragma unroll
                for (int tt = 0; tt < 4; ++tt)
                    st4(RA + swz<128>(tt * 16 + l15, w * 16 + q * 4), acc[tt] + bias);
            } else if (part == 1) {
#pragma unroll
                for (int tt = 0; tt < 4; ++tt)
                    st4(RB + swz<128>(tt * 16 + l15, w * 16 + q * 4), acc[tt] + bias);
            } else {
#pragma unroll
                for (int tt = 0; tt < 4; ++tt)
#pragma unroll
                    for (int r = 0; r < 4; ++r)
                        RC[w * 1024 + swz<64>(q * 4 + r, tt * 16 + l15)] =
                            (bf16)(acc[tt][r] + bias[r]);
            }
        }
    }
    __syncthreads();  // KEEP: removing it (r7) caused wave drift -> L2 weight
                      // eviction (FETCH +163MB) -> +32us. Lockstep is faster.

    // -------- stage 4: attention (wave w = head w), S^T = K.Q^T -------------
    bf16x8 pfPROJ[4];
    {
        // prefetch stage-5 weights: latency hidden under attention compute.
#pragma unroll
        for (int ks = 0; ks < 4; ++ks)
            pfPROJ[ks] = *(const bf16x8*)(wp + OFF_PROJ + ((w * 4 + ks) * 64 + lane) * 8);
        const int colA = w * 16 + (q & 1) * 8;  // HD=16: quads>=2 zero-padded
        const bool hi = (q >= 2);
        const bf16x8 z8 = zero8();
        bf16* const slab = RC + w * 1024;  // [16][64] swz<64>: V^T, then P
        bf16x8 Kf[4];
#pragma unroll
        for (int kt = 0; kt < 4; ++kt) {
            bf16x8 t = *(const bf16x8*)(RB + swz<128>(kt * 16 + l15, colA));
            Kf[kt] = hi ? z8 : t;
        }
        // V frags are qt-independent: load once, then the slab is free for P.
        bf16x8 Vf[2];
#pragma unroll
        for (int ks = 0; ks < 2; ++ks)
            Vf[ks] = *(const bf16x8*)(slab + swz<64>(l15, ks * 32 + q * 8));
#pragma unroll
        for (int qt = 0; qt < 4; ++qt) {
            bf16x8 t = *(const bf16x8*)(RA + swz<128>(qt * 16 + l15, colA));
            bf16x8 Qf = hi ? z8 : t;
            // MAX-FREE softmax over ktok for fixed qtok = qt*16+l15:
            // e^s normalizes identically to e^(s-mx); |s*0.25*log2e|<=~14
            // << 88, no overflow.  exp of S[kt] issues as soon as its MFMA
            // lands.  fp32 normalize BEFORE bf16 quantization.
            float P[4][4];
            float lsum = 0.f;
#pragma unroll
            for (int kt = 0; kt < 4; ++kt) {
                f32x4 S = MFMA16(Kf[kt], Qf, fzero);
#pragma unroll
                for (int r = 0; r < 4; ++r) {
                    const float sv = S[r] * 0.25f;  // HD^-0.5
                    const float e = __builtin_amdgcn_exp2f(sv * 1.4426950408889634f);
                    P[kt][r] = e;
                    lsum += e;
                }
            }
            lsum += __shfl_xor(lsum, 16);
            lsum += __shfl_xor(lsum, 32);
            const float inv = __builtin_amdgcn_rcpf(lsum);
            // normalized P -> slab as [qtok][ktok] bf16
#pragma unroll
            for (int kt = 0; kt < 4; ++kt) {
                f32x4 e4;
#pragma unroll
                for (int r = 0; r < 4; ++r) e4[r] = P[kt][r] * inv;
                st4(slab + swz<64>(l15, kt * 16 + q * 4), e4);
            }
            // O^T = V^T . P^T ; B-frag of P^T == row-contig bf16x8 of P slab
            f32x4 O = fzero;
#pragma unroll
            for (int ks = 0; ks < 2; ++ks) {
                bf16x8 Bf = *(const bf16x8*)(slab + swz<64>(l15, ks * 32 + q * 8));
                O = MFMA16(Vf[ks], Bf, O);
            }
            st4(RA + swz<128>(qt * 16 + l15, w * 16 + q * 4), O);  // over Q rows qt
        }
    }
    __syncthreads();

    // -------- stage 5: x2 += (O . w_proj)^T + b_proj; x2_bf16 -> RB ---------
    bf16x8 pfM1[8];
    {
        // prefetch stage-7 weights (kk = half*4+ks -> mt = w*2+half).
#pragma unroll
        for (int kk = 0; kk < 8; ++kk)
            pfM1[kk] = *(const bf16x8*)(wp + OFF_M1 +
                (((w * 2 + (kk >> 2)) * 4 + (kk & 3)) * 64 + lane) * 8);
        f32x4 acc[4];
#pragma unroll
        for (int tt = 0; tt < 4; ++tt) acc[tt] = fzero;
#pragma unroll
        for (int ks = 0; ks < 4; ++ks) {
#pragma unroll
            for (int tt = 0; tt < 4; ++tt) {
                bf16x8 bfr = *(const bf16x8*)(RA + swz<128>(tt * 16 + l15, ks * 32 + q * 8));
                acc[tt] = MFMA16(pfPROJ[ks], bfr, acc[tt]);
            }
        }
        const f32x4 bias = *(const f32x4*)(b_proj + w * 16 + q * 4);
#pragma unroll
        for (int tt = 0; tt < 4; ++tt) {
#pragma unroll
            for (int r = 0; r < 4; ++r) x2[tt][r] += acc[tt][r] + bias[r];
            st4(RB + swz<128>(tt * 16 + l15, w * 16 + q * 4), x2[tt]);
        }
    }
    __syncthreads();

    // -------- stage 6: n2 = LN(x2)*g2+b2 : RB -> RA -------------------------
    ln_rows(RB, RA, g2, b2, tid);
    __syncthreads();

    // -------- stage 7: hidden = gelu(w_m1^T . n2^T + b_m1), tt-outer --------
    // tt-outer: Bfr[4] (16 regs) per token tile instead of Bfr[4][4] (64) —
    // makes room for pfM1/pfM2 while keeping peak pressure at stage 3.
    // Per-output-element ks order unchanged -> numerically identical.
    // hidden (64x256): cols 0:128 -> RB, 128:256 -> RC; no mid barrier.
    bf16x8 pfM2[8];
    {
#pragma unroll
        for (int tt = 0; tt < 4; ++tt) {
            bf16x8 Bfr[4];
#pragma unroll
            for (int ks = 0; ks < 4; ++ks)
                Bfr[ks] = *(const bf16x8*)(RA + swz<128>(tt * 16 + l15, ks * 32 + q * 8));
#pragma unroll
            for (int half = 0; half < 2; ++half) {
                const int mt = w * 2 + half;  // 0..15; mt<8 -> RB, else RC
                f32x4 acc = fzero;
#pragma unroll
                for (int ks = 0; ks < 4; ++ks)
                    acc = MFMA16(pfM1[half * 4 + ks], Bfr[ks], acc);
                const f32x4 bias = *(const f32x4*)(b_m1 + mt * 16 + q * 4);
                f32x4 gl;
#pragma unroll
                for (int r = 0; r < 4; ++r) gl[r] = gelu_f(acc[r] + bias[r]);
                bf16* const dst = (mt < 8) ? RB : RC;
                st4(dst + swz<128>(tt * 16 + l15, (mt & 7) * 16 + q * 4), gl);
            }
        }
        // prefetch stage-8 weights: in flight across the barrier.
#pragma unroll
        for (int ks = 0; ks < 8; ++ks)
            pfM2[ks] = *(const bf16x8*)(wp + OFF_M2 + ((w * 8 + ks) * 64 + lane) * 8);
    }
    __syncthreads();

    // -------- stage 8: x2 += (hidden . w_m2)^T + b_m2; x2_bf16 -> RA --------
    bf16x8 pfPOST[4];
    {
        const int ct = w >> 1;  // stage-9 out-channel tile
#pragma unroll
        for (int ks = 0; ks < 4; ++ks)
            pfPOST[ks] = *(const bf16x8*)(wp + OFF_POST + ((ct * 4 + ks) * 64 + lane) * 8);
        f32x4 acc[4];
#pragma unroll
        for (int tt = 0; tt < 4; ++tt) acc[tt] = fzero;
#pragma unroll
        for (int ks = 0; ks < 8; ++ks) {
            const bf16* const srcH = (ks < 4) ? RB : RC;
            const int colb = (ks & 3) * 32 + q * 8;
#pragma unroll
            for (int tt = 0; tt < 4; ++tt) {
                bf16x8 bfr = *(const bf16x8*)(srcH + swz<128>(tt * 16 + l15, colb));
                acc[tt] = MFMA16(pfM2[ks], bfr, acc[tt]);
            }
        }
        const f32x4 bias = *(const f32x4*)(b_m2 + w * 16 + q * 4);
#pragma unroll
        for (int tt = 0; tt < 4; ++tt) {
#pragma unroll
            for (int r = 0; r < 4; ++r) x2[tt][r] += acc[tt][r] + bias[r];
            st4(RA + swz<128>(tt * 16 + l15, w * 16 + q * 4), x2[tt]);
        }
    }
    __syncthreads();

    // -------- stage 9: out^T = w_post^T . x2^T + b_post (fp32, dwordx4) -----
    // r4 mapping (proven): wave w owns ct = w>>1, token tiles (w&1)*2+{0,1}.
    {
        const int ct  = w >> 1;        // out-channel tile 0..3
        const int tt0 = (w & 1) * 2;   // token tiles tt0, tt0+1
        f32x4 acc[2];
#pragma unroll
        for (int rr = 0; rr < 2; ++rr) acc[rr] = fzero;
#pragma unroll
        for (int ks = 0; ks < 4; ++ks) {
#pragma unroll
            for (int rr = 0; rr < 2; ++rr) {
                bf16x8 bfr = *(const bf16x8*)(RA + swz<128>((tt0 + rr) * 16 + l15, ks * 32 + q * 8));
                acc[rr] = MFMA16(pfPOST[ks], bfr, acc[rr]);
            }
        }
        const f32x4 bias = *(const f32x4*)(b_post + ct * 16 + q * 4);
#pragma unroll
        for (int rr = 0; rr < 2; ++rr) {
            f32x4 v = acc[rr] + bias;
            *(f32x4*)(out + (base + (tt0 + rr) * 16 + l15) * 64 + ct * 16 + q * 4) = v;
        }
    }
}

extern "C" void kernel_launch(void* const* d_in, const int* in_sizes, int n_in,
                              void* d_out, int out_size, void* d_ws, size_t ws_size,
                              hipStream_t stream) {
    const float* feats  = (const float*)d_in[0];
    const float* w_pre  = (const float*)d_in[1];
    const float* b_pre  = (const float*)d_in[2];
    const float* g1     = (const float*)d_in[3];
    const float* b1     = (const float*)d_in[4];
    const float* w_qkv  = (const float*)d_in[5];
    const float* b_qkv  = (const float*)d_in[6];
    const float* w_proj = (const float*)d_in[7];
    const float* b_proj = (const float*)d_in[8];
    const float* g2     = (const float*)d_in[9];
    const float* b2     = (const float*)d_in[10];
    const float* w_m1   = (const float*)d_in[11];
    const float* b_m1   = (const float*)d_in[12];
    const float* w_m2   = (const float*)d_in[13];
    const float* b_m2   = (const float*)d_in[14];
    const float* w_post = (const float*)d_in[15];
    const float* b_post = (const float*)d_in[16];

    bf16* wp = (bf16*)d_ws;  // 288 KB of packed bf16 W^T A-fragments

    pack_all<<<288, 64, 0, stream>>>(w_pre, w_qkv, w_proj, w_m1, w_m2, w_post, wp);

    fused_block_kernel<<<8192, 512, 0, stream>>>(
        feats, wp, b_pre, g1, b1, b_qkv, b_proj, g2, b2, b_m1, b_m2, b_post,
        (float*)d_out);
}

// Round 15
// 566.051 us; speedup vs baseline: 1.4531x; 1.0934x over previous
//
#include <hip/hip_runtime.h>
#include <hip/hip_bf16.h>
#include <math.h>

// ---------------------------------------------------------------------------
// Fully fused transformer block, TRANSPOSED-GEMM formulation.
// One workgroup (512 thr = 8 waves) per 64-token window; 8192 windows.
// Round 15 = round 14 resubmitted verbatim (r14 hit GPUAcquisitionTimeout —
// infra failure, no data; single-variable discipline requires rerunning).
// Round 14 (base = round 13, 478.7us verified best):
//  * NEW: stage-4 QK^T switched from 16x16x32 MFMA (hd=16 -> quads 2-3 were
//    ZERO-PADDED, 50% wasted matrix work + b128 reads of half-zeros) to
//    v_mfma_f32_16x16x16_bf16 (K=16 == HD): all quads active, Kf/Qf are
//    b64 reads, zero8/cndmask removed. Dropped terms were exact zeros ->
//    bit-identical S. C/D layout of 16x16x16 == 16x16x32 (both 16x16 C,
//    row=quad*4+reg, col=lane&15) -> softmax/P/PV code untouched.
//    Guarded by __has_builtin with fallback to the r13 path.
//  KEPT from r13 (measured: 483->479us, FETCH +150MB benign at 23% BW):
//    cross-barrier weight prefetch (PRE@s0, Q@s3, PROJ@s4, M1@s5, M2@s7,
//    POST@s8); stage-7 tt-outer.
//  KEPT from r9: max-free softmax; all barriers (r7: removal -> wave drift
//  -> L2 weight eviction); LDS 48KB 3-region overlay; P^T via LDS round-trip
//  through dead V slab; launch_bounds(512,4) (r3/r5: bounds-6 spills).
// Layouts (guide §3, HW-verified): A[m=lane&15][k=quad*8+j] (K=32) or
// [k=quad*4+j] (K=16), B[k][n=lane&15], D[row=quad*4+reg][col=lane&15].
// ---------------------------------------------------------------------------

typedef __bf16 bf16;
typedef __bf16 bf16x8 __attribute__((ext_vector_type(8)));
typedef __bf16 bf16x4 __attribute__((ext_vector_type(4)));
typedef float  f32x4  __attribute__((ext_vector_type(4)));
typedef short  s16x4  __attribute__((ext_vector_type(4)));

#define MFMA16(a, b, c) __builtin_amdgcn_mfma_f32_16x16x32_bf16((a), (b), (c), 0, 0, 0)

#if __has_builtin(__builtin_amdgcn_mfma_f32_16x16x16bf16_1k)
#define HAVE_K16 1
#define MFMA16K16(a, b, c) __builtin_amdgcn_mfma_f32_16x16x16bf16_1k((a), (b), (c), 0, 0, 0)
#else
#define HAVE_K16 0
#endif

// packed-weight element offsets inside d_ws (bf16 elements)
constexpr int OFF_PRE  = 0;       // w_pre  64x128 : KT=2, MT=8  -> 16 tiles
constexpr int OFF_QKV  = 8192;    // w_qkv 128x384 : KT=4, MT=24 -> 96 tiles
constexpr int OFF_PROJ = 57344;   // w_proj128x128 : KT=4, MT=8  -> 32 tiles
constexpr int OFF_M1   = 73728;   // w_m1  128x256 : KT=4, MT=16 -> 64 tiles
constexpr int OFF_M2   = 106496;  // w_m2  256x128 : KT=8, MT=8  -> 64 tiles
constexpr int OFF_POST = 139264;  // w_post128x64  : KT=4, MT=4  -> 16 tiles
// total 147456 bf16 = 288 KB in d_ws

// XOR-swizzled row-major layout (16B chunks XOR row) -> conflict-light
// ds_read_b128 / ds_write_b64 without padding.
template <int W>
__device__ __forceinline__ int swz(int row, int col) {
    constexpr int CH = W >> 3;
    constexpr int M  = (CH - 1) < 15 ? (CH - 1) : 15;
    const int c = (col >> 3) ^ (row & M);
    return row * W + c * 8 + (col & 7);
}

__device__ __forceinline__ bf16x8 zero8() {
    bf16x8 z;
#pragma unroll
    for (int j = 0; j < 8; ++j) z[j] = (bf16)0.0f;
    return z;
}

// store 4 fp32 as 4 consecutive bf16 (8B). col base is 4-aligned -> stays
// inside one 8-elem swizzle chunk -> single ds_write_b64.
__device__ __forceinline__ void st4(bf16* p, const f32x4 v) {
    bf16x4 o;
#pragma unroll
    for (int r = 0; r < 4; ++r) o[r] = (bf16)v[r];
    *(bf16x4*)p = o;
}

// fast gelu: x * sigmoid(2u), u = 0.79788456(x + 0.044715 x^3)
__device__ __forceinline__ float gelu_f(float x) {
    const float u = 0.79788456f * x * (1.0f + 0.044715f * x * x);
    const float e = __builtin_amdgcn_exp2f(u * 2.8853900817779268f);  // e^(2u)
    return x - x * __builtin_amdgcn_rcpf(e + 1.0f);  // robust at e->inf
}

// ---------------------------------------------------------------------------
// Weight packer: fp32 W[K][N] -> A-frag tiles of W^T (== B-frag tiles of W).
// Tile (mt,kt): lane l, frag[j] = W[kt*32 + (l>>4)*8 + j][mt*16 + (l&15)].
// All six weights in ONE kernel (288 blocks) to avoid 6 launch latencies.
// ---------------------------------------------------------------------------
__global__ void pack_all(const float* __restrict__ w_pre,
                         const float* __restrict__ w_qkv,
                         const float* __restrict__ w_proj,
                         const float* __restrict__ w_m1,
                         const float* __restrict__ w_m2,
                         const float* __restrict__ w_post,
                         bf16* __restrict__ dst) {
    const int t = blockIdx.x;
    const float* src;
    int Ncol, KT, off, t0;
    if (t < 16)       { src = w_pre;  Ncol = 128; KT = 2; off = OFF_PRE;  t0 = 0; }
    else if (t < 112) { src = w_qkv;  Ncol = 384; KT = 4; off = OFF_QKV;  t0 = 16; }
    else if (t < 144) { src = w_proj; Ncol = 128; KT = 4; off = OFF_PROJ; t0 = 112; }
    else if (t < 208) { src = w_m1;   Ncol = 256; KT = 4; off = OFF_M1;   t0 = 144; }
    else if (t < 272) { src = w_m2;   Ncol = 128; KT = 8; off = OFF_M2;   t0 = 208; }
    else              { src = w_post; Ncol = 64;  KT = 4; off = OFF_POST; t0 = 272; }
    const int tile = t - t0;
    const int lane = threadIdx.x;
    const int mt = tile / KT, kt = tile - mt * KT;
    const int n  = mt * 16 + (lane & 15);
    const int k0 = kt * 32 + (lane >> 4) * 8;
    bf16x8 v;
#pragma unroll
    for (int j = 0; j < 8; ++j) v[j] = (bf16)src[(k0 + j) * Ncol + n];
    // NOTE: destination MUST include the per-weight region offset `off`.
    *(bf16x8*)(dst + off + ((long)(tile * 64 + lane)) * 8) = v;
}

// LayerNorm over 128 channels: 8 lanes per row, shuffle-reduce, bf16 out.
__device__ __forceinline__ void ln_rows(const bf16* __restrict__ in,
                                        bf16* __restrict__ outb,
                                        const float* __restrict__ g,
                                        const float* __restrict__ b, int tid) {
    const int row = tid >> 3, sub = tid & 7;
    bf16x8 c0 = *(const bf16x8*)(in + swz<128>(row, sub * 16));
    bf16x8 c1 = *(const bf16x8*)(in + swz<128>(row, sub * 16 + 8));
    float v[16];
#pragma unroll
    for (int j = 0; j < 8; ++j) { v[j] = (float)c0[j]; v[8 + j] = (float)c1[j]; }
    float s = 0.f, ss = 0.f;
#pragma unroll
    for (int j = 0; j < 16; ++j) { s += v[j]; ss += v[j] * v[j]; }
#pragma unroll
    for (int m = 1; m <= 4; m <<= 1) {
        s += __shfl_xor(s, m);
        ss += __shfl_xor(ss, m);
    }
    const float mu   = s * (1.0f / 128.0f);
    const float rstd = __builtin_amdgcn_rsqf(ss * (1.0f / 128.0f) - mu * mu + 1e-5f);
    bf16x8 o0, o1;
#pragma unroll
    for (int j = 0; j < 8; ++j) {
        o0[j] = (bf16)((v[j] - mu) * rstd * g[sub * 16 + j] + b[sub * 16 + j]);
        o1[j] = (bf16)((v[8 + j] - mu) * rstd * g[sub * 16 + 8 + j] + b[sub * 16 + 8 + j]);
    }
    *(bf16x8*)(outb + swz<128>(row, sub * 16)) = o0;
    *(bf16x8*)(outb + swz<128>(row, sub * 16 + 8)) = o1;
}

__global__ __launch_bounds__(512, 4)
void fused_block_kernel(const float* __restrict__ feats,
                        const bf16* __restrict__ wp,
                        const float* __restrict__ b_pre,
                        const float* __restrict__ g1, const float* __restrict__ b1,
                        const float* __restrict__ b_qkv,
                        const float* __restrict__ b_proj,
                        const float* __restrict__ g2, const float* __restrict__ b2,
                        const float* __restrict__ b_m1,
                        const float* __restrict__ b_m2,
                        const float* __restrict__ b_post,
                        float* __restrict__ out) {
    // 48 KB static LDS, three 16 KB regions, time-multiplexed:
    //  RA: feats(8KB, swz<64>) -> n1 -> Q -> O -> n2 -> x2_bf16(post input)
    //  RB: x2_bf16(LN1 in) -> K -> x2_bf16(LN2 in) -> hidden[:,0:128]
    //  RC: per-wave slabs (V^T then P, 1024 elems each) -> hidden[:,128:256]
    // Lifetime rules: a region is overwritten only after (a) an all-wave
    // barrier past its last cross-wave read, or (b) it is same-wave-private.
    __shared__ __align__(16) bf16 RA[64 * 128];
    __shared__ __align__(16) bf16 RB[64 * 128];
    __shared__ __align__(16) bf16 RC[64 * 128];

    const int tid  = threadIdx.x;
    const int w    = tid >> 6;   // wave 0..7 == head / out-channel-tile owner
    const int lane = tid & 63;
    const int q    = lane >> 4;  // quad
    const int l15  = lane & 15;
    const long base = (long)blockIdx.x * 64;
    const f32x4 fzero = {0.f, 0.f, 0.f, 0.f};

    // -------- stage 0: feats (64x64 fp32) -> RA bf16, swizzled --------------
    bf16x8 pfPRE[2];
    {
        const int row = tid >> 3, ch = tid & 7;
        const float* src = feats + (base + row) * 64 + ch * 8;
        float4 a = *(const float4*)src;
        float4 b = *(const float4*)(src + 4);
        // prefetch stage-1 weights: in flight during cvt/store, drained at
        // the barrier (compiler emits vmcnt(0) before s_barrier).
#pragma unroll
        for (int ks = 0; ks < 2; ++ks)
            pfPRE[ks] = *(const bf16x8*)(wp + OFF_PRE + ((w * 2 + ks) * 64 + lane) * 8);
        bf16x8 v;
        v[0] = (bf16)a.x; v[1] = (bf16)a.y; v[2] = (bf16)a.z; v[3] = (bf16)a.w;
        v[4] = (bf16)b.x; v[5] = (bf16)b.y; v[6] = (bf16)b.z; v[7] = (bf16)b.w;
        *(bf16x8*)(RA + swz<64>(row, ch * 8)) = v;
    }
    __syncthreads();

    // residual stream in regs: x2[tt][r] = x2[token tt*16+l15][ch w*16+q*4+r]
    f32x4 x2[4];

    // -------- stage 1: x2^T = w_pre^T . feats^T + b_pre; x2_bf16 -> RB ------
    {
        f32x4 acc[4];
#pragma unroll
        for (int tt = 0; tt < 4; ++tt) acc[tt] = fzero;
#pragma unroll
        for (int ks = 0; ks < 2; ++ks) {
#pragma unroll
            for (int tt = 0; tt < 4; ++tt) {
                bf16x8 bfr = *(const bf16x8*)(RA + swz<64>(tt * 16 + l15, ks * 32 + q * 8));
                acc[tt] = MFMA16(pfPRE[ks], bfr, acc[tt]);
            }
        }
        const f32x4 bias = *(const f32x4*)(b_pre + w * 16 + q * 4);
#pragma unroll
        for (int tt = 0; tt < 4; ++tt) {
#pragma unroll
            for (int r = 0; r < 4; ++r) x2[tt][r] = acc[tt][r] + bias[r];
            st4(RB + swz<128>(tt * 16 + l15, w * 16 + q * 4), x2[tt]);
        }
    }
    __syncthreads();

    // -------- stage 2: n1 = LN(x2)*g1+b1 : RB -> RA -------------------------
    ln_rows(RB, RA, g1, b1, tid);
    __syncthreads();

    // -------- stage 3: qkv^T = w_qkv^T . n1^T + b_qkv -----------------------
    // n1 consumed into regs first, then RA is reused for Q (barrier between).
    // wave w: Q head w -> RA (cols 16w..), K head w -> RB (cols 16w..),
    // V head w -> RC slab w, transposed [ch][tok].
    // Part-0 (Q) weights prefetched during the Bfr ds_read preload + barrier.
    {
        bf16x8 pfQ[4];
#pragma unroll
        for (int ks = 0; ks < 4; ++ks)
            pfQ[ks] = *(const bf16x8*)(wp + OFF_QKV + ((w * 4 + ks) * 64 + lane) * 8);
        bf16x8 Bfr[4][4];
#pragma unroll
        for (int ks = 0; ks < 4; ++ks)
#pragma unroll
            for (int tt = 0; tt < 4; ++tt)
                Bfr[ks][tt] = *(const bf16x8*)(RA + swz<128>(tt * 16 + l15, ks * 32 + q * 8));
        __syncthreads();  // all waves done reading n1; RA writable
#pragma unroll
        for (int part = 0; part < 3; ++part) {
            const int mt = part * 8 + w;
            f32x4 acc[4];
#pragma unroll
            for (int tt = 0; tt < 4; ++tt) acc[tt] = fzero;
#pragma unroll
            for (int ks = 0; ks < 4; ++ks) {
                bf16x8 afr = (part == 0)
                    ? pfQ[ks]
                    : *(const bf16x8*)(wp + OFF_QKV + ((mt * 4 + ks) * 64 + lane) * 8);
#pragma unroll
                for (int tt = 0; tt < 4; ++tt) acc[tt] = MFMA16(afr, Bfr[ks][tt], acc[tt]);
            }
            const f32x4 bias = *(const f32x4*)(b_qkv + mt * 16 + q * 4);
            if (part == 0) {
#pragma unroll
                for (int tt = 0; tt < 4; ++tt)
                    st4(RA + swz<128>(tt * 16 + l15, w * 16 + q * 4), acc[tt] + bias);
            } else if (part == 1) {
#pragma unroll
                for (int tt = 0; tt < 4; ++tt)
                    st4(RB + swz<128>(tt * 16 + l15, w * 16 + q * 4), acc[tt] + bias);
            } else {
#pragma unroll
                for (int tt = 0; tt < 4; ++tt)
#pragma unroll
                    for (int r = 0; r < 4; ++r)
                        RC[w * 1024 + swz<64>(q * 4 + r, tt * 16 + l15)] =
                            (bf16)(acc[tt][r] + bias[r]);
            }
        }
    }
    __syncthreads();  // KEEP: removing it (r7) caused wave drift -> L2 weight
                      // eviction (FETCH +163MB) -> +32us. Lockstep is faster.

    // -------- stage 4: attention (wave w = head w), S^T = K.Q^T -------------
    bf16x8 pfPROJ[4];
    {
        // prefetch stage-5 weights: latency hidden under attention compute.
#pragma unroll
        for (int ks = 0; ks < 4; ++ks)
            pfPROJ[ks] = *(const bf16x8*)(wp + OFF_PROJ + ((w * 4 + ks) * 64 + lane) * 8);
        bf16* const slab = RC + w * 1024;  // [16][64] swz<64>: V^T, then P
        // V frags are qt-independent: load once, then the slab is free for P.
        bf16x8 Vf[2];
#pragma unroll
        for (int ks = 0; ks < 2; ++ks)
            Vf[ks] = *(const bf16x8*)(slab + swz<64>(l15, ks * 32 + q * 8));
#if HAVE_K16
        // K=16 MFMA == HD: all quads active, b64 frags, no zero padding.
        // A[m=ktok l15][k=hd q*4+j], B[k=hd q*4+j][n=qtok l15]; C/D layout
        // identical to the 16x16x32 shape -> downstream code unchanged.
        const int colA = w * 16 + q * 4;
        s16x4 Kf[4];
#pragma unroll
        for (int kt = 0; kt < 4; ++kt)
            Kf[kt] = *(const s16x4*)(RB + swz<128>(kt * 16 + l15, colA));
#else
        const int colA = w * 16 + (q & 1) * 8;  // HD=16: quads>=2 zero-padded
        const bool hi = (q >= 2);
        const bf16x8 z8 = zero8();
        bf16x8 Kf[4];
#pragma unroll
        for (int kt = 0; kt < 4; ++kt) {
            bf16x8 t = *(const bf16x8*)(RB + swz<128>(kt * 16 + l15, colA));
            Kf[kt] = hi ? z8 : t;
        }
#endif
#pragma unroll
        for (int qt = 0; qt < 4; ++qt) {
#if HAVE_K16
            s16x4 Qf = *(const s16x4*)(RA + swz<128>(qt * 16 + l15, colA));
#else
            bf16x8 t = *(const bf16x8*)(RA + swz<128>(qt * 16 + l15, colA));
            bf16x8 Qf = hi ? z8 : t;
#endif
            // MAX-FREE softmax over ktok for fixed qtok = qt*16+l15:
            // e^s normalizes identically to e^(s-mx); |s*0.25*log2e|<=~14
            // << 88, no overflow.  exp of S[kt] issues as soon as its MFMA
            // lands.  fp32 normalize BEFORE bf16 quantization.
            float P[4][4];
            float lsum = 0.f;
#pragma unroll
            for (int kt = 0; kt < 4; ++kt) {
#if HAVE_K16
                f32x4 S = MFMA16K16(Kf[kt], Qf, fzero);
#else
                f32x4 S = MFMA16(Kf[kt], Qf, fzero);
#endif
#pragma unroll
                for (int r = 0; r < 4; ++r) {
                    const float sv = S[r] * 0.25f;  // HD^-0.5
                    const float e = __builtin_amdgcn_exp2f(sv * 1.4426950408889634f);
                    P[kt][r] = e;
                    lsum += e;
                }
            }
            lsum += __shfl_xor(lsum, 16);
            lsum += __shfl_xor(lsum, 32);
            const float inv = __builtin_amdgcn_rcpf(lsum);
            // normalized P -> slab as [qtok][ktok] bf16
#pragma unroll
            for (int kt = 0; kt < 4; ++kt) {
                f32x4 e4;
#pragma unroll
                for (int r = 0; r < 4; ++r) e4[r] = P[kt][r] * inv;
                st4(slab + swz<64>(l15, kt * 16 + q * 4), e4);
            }
            // O^T = V^T . P^T ; B-frag of P^T == row-contig bf16x8 of P slab
            f32x4 O = fzero;
#pragma unroll
            for (int ks = 0; ks < 2; ++ks) {
                bf16x8 Bf = *(const bf16x8*)(slab + swz<64>(l15, ks * 32 + q * 8));
                O = MFMA16(Vf[ks], Bf, O);
            }
            st4(RA + swz<128>(qt * 16 + l15, w * 16 + q * 4), O);  // over Q rows qt
        }
    }
    __syncthreads();

    // -------- stage 5: x2 += (O . w_proj)^T + b_proj; x2_bf16 -> RB ---------
    bf16x8 pfM1[8];
    {
        // prefetch stage-7 weights (kk = half*4+ks -> mt = w*2+half).
#pragma unroll
        for (int kk = 0; kk < 8; ++kk)
            pfM1[kk] = *(const bf16x8*)(wp + OFF_M1 +
                (((w * 2 + (kk >> 2)) * 4 + (kk & 3)) * 64 + lane) * 8);
        f32x4 acc[4];
#pragma unroll
        for (int tt = 0; tt < 4; ++tt) acc[tt] = fzero;
#pragma unroll
        for (int ks = 0; ks < 4; ++ks) {
#pragma unroll
            for (int tt = 0; tt < 4; ++tt) {
                bf16x8 bfr = *(const bf16x8*)(RA + swz<128>(tt * 16 + l15, ks * 32 + q * 8));
                acc[tt] = MFMA16(pfPROJ[ks], bfr, acc[tt]);
            }
        }
        const f32x4 bias = *(const f32x4*)(b_proj + w * 16 + q * 4);
#pragma unroll
        for (int tt = 0; tt < 4; ++tt) {
#pragma unroll
            for (int r = 0; r < 4; ++r) x2[tt][r] += acc[tt][r] + bias[r];
            st4(RB + swz<128>(tt * 16 + l15, w * 16 + q * 4), x2[tt]);
        }
    }
    __syncthreads();

    // -------- stage 6: n2 = LN(x2)*g2+b2 : RB -> RA -------------------------
    ln_rows(RB, RA, g2, b2, tid);
    __syncthreads();

    // -------- stage 7: hidden = gelu(w_m1^T . n2^T + b_m1), tt-outer --------
    // tt-outer: Bfr[4] (16 regs) per token tile instead of Bfr[4][4] (64) —
    // makes room for pfM1/pfM2 while keeping peak pressure at stage 3.
    // hidden (64x256): cols 0:128 -> RB, 128:256 -> RC; no mid barrier.
    bf16x8 pfM2[8];
    {
#pragma unroll
        for (int tt = 0; tt < 4; ++tt) {
            bf16x8 Bfr[4];
#pragma unroll
            for (int ks = 0; ks < 4; ++ks)
                Bfr[ks] = *(const bf16x8*)(RA + swz<128>(tt * 16 + l15, ks * 32 + q * 8));
#pragma unroll
            for (int half = 0; half < 2; ++half) {
                const int mt = w * 2 + half;  // 0..15; mt<8 -> RB, else RC
                f32x4 acc = fzero;
#pragma unroll
                for (int ks = 0; ks < 4; ++ks)
                    acc = MFMA16(pfM1[half * 4 + ks], Bfr[ks], acc);
                const f32x4 bias = *(const f32x4*)(b_m1 + mt * 16 + q * 4);
                f32x4 gl;
#pragma unroll
                for (int r = 0; r < 4; ++r) gl[r] = gelu_f(acc[r] + bias[r]);
                bf16* const dst = (mt < 8) ? RB : RC;
                st4(dst + swz<128>(tt * 16 + l15, (mt & 7) * 16 + q * 4), gl);
            }
        }
        // prefetch stage-8 weights: in flight across the barrier.
#pragma unroll
        for (int ks = 0; ks < 8; ++ks)
            pfM2[ks] = *(const bf16x8*)(wp + OFF_M2 + ((w * 8 + ks) * 64 + lane) * 8);
    }
    __syncthreads();

    // -------- stage 8: x2 += (hidden . w_m2)^T + b_m2; x2_bf16 -> RA --------
    bf16x8 pfPOST[4];
    {
        const int ct = w >> 1;  // stage-9 out-channel tile
#pragma unroll
        for (int ks = 0; ks < 4; ++ks)
            pfPOST[ks] = *(const bf16x8*)(wp + OFF_POST + ((ct * 4 + ks) * 64 + lane) * 8);
        f32x4 acc[4];
#pragma unroll
        for (int tt = 0; tt < 4; ++tt) acc[tt] = fzero;
#pragma unroll
        for (int ks = 0; ks < 8; ++ks) {
            const bf16* const srcH = (ks < 4) ? RB : RC;
            const int colb = (ks & 3) * 32 + q * 8;
#pragma unroll
            for (int tt = 0; tt < 4; ++tt) {
                bf16x8 bfr = *(const bf16x8*)(srcH + swz<128>(tt * 16 + l15, colb));
                acc[tt] = MFMA16(pfM2[ks], bfr, acc[tt]);
            }
        }
        const f32x4 bias = *(const f32x4*)(b_m2 + w * 16 + q * 4);
#pragma unroll
        for (int tt = 0; tt < 4; ++tt) {
#pragma unroll
            for (int r = 0; r < 4; ++r) x2[tt][r] += acc[tt][r] + bias[r];
            st4(RA + swz<128>(tt * 16 + l15, w * 16 + q * 4), x2[tt]);
        }
    }
    __syncthreads();

    // -------- stage 9: out^T = w_post^T . x2^T + b_post (fp32, dwordx4) -----
    // r4 mapping (proven): wave w owns ct = w>>1, token tiles (w&1)*2+{0,1}.
    {
        const int ct  = w >> 1;        // out-channel tile 0..3
        const int tt0 = (w & 1) * 2;   // token tiles tt0, tt0+1
        f32x4 acc[2];
#pragma unroll
        for (int rr = 0; rr < 2; ++rr) acc[rr] = fzero;
#pragma unroll
        for (int ks = 0; ks < 4; ++ks) {
#pragma unroll
            for (int rr = 0; rr < 2; ++rr) {
                bf16x8 bfr = *(const bf16x8*)(RA + swz<128>((tt0 + rr) * 16 + l15, ks * 32 + q * 8));
                acc[rr] = MFMA16(pfPOST[ks], bfr, acc[rr]);
            }
        }
        const f32x4 bias = *(const f32x4*)(b_post + ct * 16 + q * 4);
#pragma unroll
        for (int rr = 0; rr < 2; ++rr) {
            f32x4 v = acc[rr] + bias;
            *(f32x4*)(out + (base + (tt0 + rr) * 16 + l15) * 64 + ct * 16 + q * 4) = v;
        }
    }
}

extern "C" void kernel_launch(void* const* d_in, const int* in_sizes, int n_in,
                              void* d_out, int out_size, void* d_ws, size_t ws_size,
                              hipStream_t stream) {
    const float* feats  = (const float*)d_in[0];
    const float* w_pre  = (const float*)d_in[1];
    const float* b_pre  = (const float*)d_in[2];
    const float* g1     = (const float*)d_in[3];
    const float* b1     = (const float*)d_in[4];
    const float* w_qkv  = (const float*)d_in[5];
    const float* b_qkv  = (const float*)d_in[6];
    const float* w_proj = (const float*)d_in[7];
    const float* b_proj = (const float*)d_in[8];
    const float* g2     = (const float*)d_in[9];
    const float* b2     = (const float*)d_in[10];
    const float* w_m1   = (const float*)d_in[11];
    const float* b_m1   = (const float*)d_in[12];
    const float* w_m2   = (const float*)d_in[13];
    const float* b_m2   = (const float*)d_in[14];
    const float* w_post = (const float*)d_in[15];
    const float* b_post = (const float*)d_in[16];

    bf16* wp = (bf16*)d_ws;  // 288 KB of packed bf16 W^T A-fragments

    pack_all<<<288, 64, 0, stream>>>(w_pre, w_qkv, w_proj, w_m1, w_m2, w_post, wp);

    fused_block_kernel<<<8192, 512, 0, stream>>>(
        feats, wp, b_pre, g1, b1, b_qkv, b_proj, g2, b2, b_m1, b_m2, b_post,
        (float*)d_out);
}